// Round 4
// baseline (617.867 us; speedup 1.0000x reference)
//
#include <hip/hip_runtime.h>

typedef unsigned short u16;
typedef unsigned int u32;
typedef __attribute__((ext_vector_type(8))) short bf16x8;
typedef __attribute__((ext_vector_type(4))) float f32x4;

#define HID 2048
#define S_LEN 1024
#define BATCH 2
#define G_KV 8
#define R_REP 4
#define HD 64
#define NQKV 3072  // 2048 q + 512 k + 512 v

__device__ __forceinline__ u16 f2bf(float f) {
    union { u32 u; float ff; } x; x.ff = f;
    u32 u = x.u;
    u += 0x7FFFu + ((u >> 16) & 1u);
    return (u16)(u >> 16);
}
__device__ __forceinline__ float bf2f(u16 v) {
    union { u32 u; float f; } x; x.u = ((u32)v) << 16; return x.f;
}
__device__ __forceinline__ void unpack8(uint4 u, float* out) {
    const u16* p = (const u16*)&u;
#pragma unroll
    for (int i = 0; i < 8; ++i) out[i] = bf2f(p[i]);
}

// ------- Transpose+convert: in fp32 [K][N] -> out bf16 [N][K] -------
__global__ __launch_bounds__(256) void transpose_cvt(const float* __restrict__ in,
                                                     u16* __restrict__ out,
                                                     int K, int N) {
    __shared__ float tile[32][33];
    int n0 = blockIdx.x * 32, k0 = blockIdx.y * 32;
    int tx = threadIdx.x, ty = threadIdx.y;
#pragma unroll
    for (int j = 0; j < 4; ++j)
        tile[ty + j * 8][tx] = in[(size_t)(k0 + ty + j * 8) * N + n0 + tx];
    __syncthreads();
#pragma unroll
    for (int j = 0; j < 4; ++j)
        out[(size_t)(n0 + ty + j * 8) * K + k0 + tx] = f2bf(tile[tx][ty + j * 8]);
}

// ------- QKV GEMM: Y = X(fp32)[2048,2048] @ W + b, scatter bf16 q/k/v -------
// WT bf16 [NQKV][2048]. 64x64 tile, 4 waves, K-step 32, mfma 16x16x32 bf16.
__global__ __launch_bounds__(256) void gemm_qkv(const float* __restrict__ X,
                                                const u16* __restrict__ WT,
                                                const float* __restrict__ bq,
                                                const float* __restrict__ bk,
                                                const float* __restrict__ bv,
                                                u16* __restrict__ qb,
                                                u16* __restrict__ kb,
                                                u16* __restrict__ vb) {
    __shared__ __align__(16) u16 As[64 * 40];
    __shared__ __align__(16) u16 Bs[64 * 40];
    int tid = threadIdx.x;
    int w = tid >> 6, lane = tid & 63, quad = lane >> 4, l16 = lane & 15;
    int m0 = blockIdx.y * 64, n0 = blockIdx.x * 64;
    int lr = tid >> 2, lc = (tid & 3) * 8;

    f32x4 acc[4];
#pragma unroll
    for (int i = 0; i < 4; ++i) acc[i] = (f32x4){0.f, 0.f, 0.f, 0.f};

    for (int k0 = 0; k0 < 2048; k0 += 32) {
        // stage A: fp32 -> bf16 on the fly
        const float* xr = &X[(size_t)(m0 + lr) * 2048 + k0 + lc];
        float4 a0 = *(const float4*)xr;
        float4 a1 = *(const float4*)(xr + 4);
        u16 tmp[8] = {f2bf(a0.x), f2bf(a0.y), f2bf(a0.z), f2bf(a0.w),
                      f2bf(a1.x), f2bf(a1.y), f2bf(a1.z), f2bf(a1.w)};
        *(uint4*)&As[lr * 40 + lc] = *(const uint4*)tmp;
        // stage B: bf16 copy
        *(uint4*)&Bs[lr * 40 + lc] = *(const uint4*)&WT[(size_t)(n0 + lr) * 2048 + k0 + lc];
        __syncthreads();
        bf16x8 a = *(const bf16x8*)&As[(w * 16 + l16) * 40 + quad * 8];
#pragma unroll
        for (int nt = 0; nt < 4; ++nt) {
            bf16x8 bfr = *(const bf16x8*)&Bs[(nt * 16 + l16) * 40 + quad * 8];
            acc[nt] = __builtin_amdgcn_mfma_f32_16x16x32_bf16(a, bfr, acc[nt], 0, 0, 0);
        }
        __syncthreads();
    }

#pragma unroll
    for (int nt = 0; nt < 4; ++nt) {
        int n = n0 + nt * 16 + l16;
        float bias;
        if (n < 2048) bias = bq[n];
        else if (n < 2560) bias = bk[n - 2048];
        else bias = bv[n - 2560];
#pragma unroll
        for (int reg = 0; reg < 4; ++reg) {
            int m = m0 + w * 16 + quad * 4 + reg;  // C/D: row=quad*4+reg, col=l16
            float val = acc[nt][reg] + bias;
            int b = m >> 10, s = m & 1023;
            u16 bfv = f2bf(val);
            if (n < 2048) {
                int g = n >> 8, r = (n >> 6) & 3, d = n & 63;
                qb[((((size_t)(b * G_KV + g) * R_REP + r) * S_LEN) + s) * HD + d] = bfv;
            } else if (n < 2560) {
                int n2 = n - 2048, g = n2 >> 6, d = n2 & 63;
                kb[(((size_t)(b * G_KV + g) * S_LEN) + s) * HD + d] = bfv;
            } else {
                int n2 = n - 2560, g = n2 >> 6, d = n2 & 63;
                vb[(((size_t)(b * G_KV + g) * S_LEN) + s) * HD + d] = bfv;
            }
        }
    }
}

// ------- Attention: flash-style, VALU, mask fp32 -------
// grid = B*G*R*(S/64) = 1024 blocks, 256 threads.
__global__ __launch_bounds__(256) void attn_kernel(const u16* __restrict__ qbuf,
                                                   const u16* __restrict__ kbuf,
                                                   const u16* __restrict__ vbuf,
                                                   const float* __restrict__ mask,
                                                   u16* __restrict__ aout) {
    __shared__ __align__(16) float Ks[64 * 68];
    __shared__ __align__(16) float Vs[64 * 68];
    __shared__ __align__(16) float Ms[64 * 68];
    __shared__ float l_acc[64];

    int bid = blockIdx.x;
    int qblk = bid & 15, r = (bid >> 4) & 3, g = (bid >> 6) & 7, b = bid >> 9;
    int tid = threadIdx.x, q = tid & 63, grp = tid >> 6;
    int s = qblk * 64 + q, s0 = qblk * 64;

    const u16* qrow = qbuf + ((((size_t)(b * G_KV + g) * R_REP + r) * S_LEN) + s) * HD;
    float qv[64];
#pragma unroll
    for (int c = 0; c < 8; ++c) {
        uint4 u = *(const uint4*)(qrow + c * 8);
        float f[8];
        unpack8(u, f);
#pragma unroll
        for (int i = 0; i < 8; ++i) qv[c * 8 + i] = f[i] * 0.125f;  // fold 1/sqrt(64)
    }

    float o[64];
#pragma unroll
    for (int d = 0; d < 64; ++d) o[d] = 0.f;
    float l = 0.f;

    const u16* kbase = kbuf + (size_t)(b * G_KV + g) * S_LEN * HD;
    const u16* vbase = vbuf + (size_t)(b * G_KV + g) * S_LEN * HD;
    const float* mbase = mask + ((size_t)b * S_LEN + s0) * S_LEN;

    int srow = tid >> 2, scg = (tid & 3) * 16;

    for (int kt = 0; kt < 16; ++kt) {
        {
            const u16* kr = kbase + (size_t)(kt * 64 + srow) * HD + scg;
            uint4 a0 = *(const uint4*)(kr);
            uint4 a1 = *(const uint4*)(kr + 8);
            float f[16];
            unpack8(a0, f); unpack8(a1, f + 8);
#pragma unroll
            for (int i = 0; i < 16; ++i) Ks[srow * 68 + scg + i] = f[i];

            const u16* vr = vbase + (size_t)(kt * 64 + srow) * HD + scg;
            uint4 b0 = *(const uint4*)(vr);
            uint4 b1 = *(const uint4*)(vr + 8);
            unpack8(b0, f); unpack8(b1, f + 8);
#pragma unroll
            for (int i = 0; i < 16; ++i) Vs[srow * 68 + scg + i] = f[i];

            const float* mr = mbase + (size_t)srow * S_LEN + kt * 64 + scg;
#pragma unroll
            for (int i = 0; i < 4; ++i)
                *(float4*)&Ms[srow * 68 + scg + i * 4] = *(const float4*)(mr + i * 4);
        }
        __syncthreads();

        for (int j = 0; j < 16; ++j) {
            int kk = grp * 16 + j;
            const float* krow = &Ks[kk * 68];
            float dot = 0.f;
#pragma unroll
            for (int dc = 0; dc < 16; ++dc) {
                float4 k4 = *(const float4*)&krow[dc * 4];
                dot += qv[dc * 4 + 0] * k4.x + qv[dc * 4 + 1] * k4.y +
                       qv[dc * 4 + 2] * k4.z + qv[dc * 4 + 3] * k4.w;
            }
            float e = __expf(dot * Ms[q * 68 + kk]);
            l += e;
            const float* vrow = &Vs[kk * 68];
#pragma unroll
            for (int dc = 0; dc < 16; ++dc) {
                float4 v4 = *(const float4*)&vrow[dc * 4];
                o[dc * 4 + 0] += e * v4.x; o[dc * 4 + 1] += e * v4.y;
                o[dc * 4 + 2] += e * v4.z; o[dc * 4 + 3] += e * v4.w;
            }
        }
        __syncthreads();
    }

    // cross-group reduction via LDS (reuse Ks as o_acc, stride 65)
    float* o_acc = Ks;
    for (int gs = 0; gs < 4; ++gs) {
        if (grp == gs) {
            if (gs == 0) {
#pragma unroll
                for (int d = 0; d < 64; ++d) o_acc[q * 65 + d] = o[d];
                l_acc[q] = l;
            } else {
#pragma unroll
                for (int d = 0; d < 64; ++d) o_acc[q * 65 + d] += o[d];
                l_acc[q] += l;
            }
        }
        __syncthreads();
    }

    float inv = 1.0f / l_acc[q];
    int d0 = grp * 16;
    u16 outv[16];
#pragma unroll
    for (int i = 0; i < 16; ++i) outv[i] = f2bf(o_acc[q * 65 + d0 + i] * inv);
    u16* dst = aout + ((size_t)(b * S_LEN + s)) * HID + (g * R_REP + r) * HD + d0;
    *(uint4*)dst = ((uint4*)outv)[0];
    *((uint4*)(dst + 8)) = ((uint4*)outv)[1];
}

// ------- Output GEMM: out = A(bf16) @ Wo + bo + x(fp32), out FP32 -------
__global__ __launch_bounds__(256) void gemm_o(const u16* __restrict__ A,
                                              const u16* __restrict__ WT,
                                              const float* __restrict__ bo,
                                              const float* __restrict__ Xres,
                                              float* __restrict__ out) {
    __shared__ __align__(16) u16 As[64 * 40];
    __shared__ __align__(16) u16 Bs[64 * 40];
    int tid = threadIdx.x;
    int w = tid >> 6, lane = tid & 63, quad = lane >> 4, l16 = lane & 15;
    int m0 = blockIdx.y * 64, n0 = blockIdx.x * 64;
    int lr = tid >> 2, lc = (tid & 3) * 8;

    f32x4 acc[4];
#pragma unroll
    for (int i = 0; i < 4; ++i) acc[i] = (f32x4){0.f, 0.f, 0.f, 0.f};

    for (int k0 = 0; k0 < 2048; k0 += 32) {
        *(uint4*)&As[lr * 40 + lc] = *(const uint4*)&A[(size_t)(m0 + lr) * 2048 + k0 + lc];
        *(uint4*)&Bs[lr * 40 + lc] = *(const uint4*)&WT[(size_t)(n0 + lr) * 2048 + k0 + lc];
        __syncthreads();
        bf16x8 a = *(const bf16x8*)&As[(w * 16 + l16) * 40 + quad * 8];
#pragma unroll
        for (int nt = 0; nt < 4; ++nt) {
            bf16x8 bfr = *(const bf16x8*)&Bs[(nt * 16 + l16) * 40 + quad * 8];
            acc[nt] = __builtin_amdgcn_mfma_f32_16x16x32_bf16(a, bfr, acc[nt], 0, 0, 0);
        }
        __syncthreads();
    }

#pragma unroll
    for (int nt = 0; nt < 4; ++nt) {
        int n = n0 + nt * 16 + l16;
        float bias = bo[n];
#pragma unroll
        for (int reg = 0; reg < 4; ++reg) {
            int m = m0 + w * 16 + quad * 4 + reg;
            float val = acc[nt][reg] + bias + Xres[(size_t)m * 2048 + n];
            out[(size_t)m * 2048 + n] = val;   // FP32 store — d_out is float*
        }
    }
}

extern "C" void kernel_launch(void* const* d_in, const int* in_sizes, int n_in,
                              void* d_out, int out_size, void* d_ws, size_t ws_size,
                              hipStream_t stream) {
    const float* x    = (const float*)d_in[0];
    const float* mask = (const float*)d_in[1];
    const float* Wq   = (const float*)d_in[2];
    const float* bq   = (const float*)d_in[3];
    const float* Wk   = (const float*)d_in[4];
    const float* bk   = (const float*)d_in[5];
    const float* Wv   = (const float*)d_in[6];
    const float* bv   = (const float*)d_in[7];
    const float* Wo   = (const float*)d_in[8];
    const float* bo   = (const float*)d_in[9];
    float* out = (float*)d_out;

    u16* ws = (u16*)d_ws;
    size_t off = 0;
    u16* WqkvT = ws + off; off += (size_t)NQKV * 2048;                        // bf16 elems
    u16* WoT   = ws + off; off += (size_t)2048 * 2048;
    u16* q_buf = ws + off; off += (size_t)BATCH * G_KV * R_REP * S_LEN * HD;
    u16* k_buf = ws + off; off += (size_t)BATCH * G_KV * S_LEN * HD;
    u16* v_buf = ws + off; off += (size_t)BATCH * G_KV * S_LEN * HD;
    u16* a_out = ws + off; off += (size_t)2048 * 2048;                        // ~42 MB total

    dim3 tb(32, 8);
    transpose_cvt<<<dim3(64, 64), tb, 0, stream>>>(Wq, WqkvT, 2048, 2048);
    transpose_cvt<<<dim3(16, 64), tb, 0, stream>>>(Wk, WqkvT + (size_t)2048 * 2048, 2048, 512);
    transpose_cvt<<<dim3(16, 64), tb, 0, stream>>>(Wv, WqkvT + (size_t)2560 * 2048, 2048, 512);
    transpose_cvt<<<dim3(64, 64), tb, 0, stream>>>(Wo, WoT, 2048, 2048);

    gemm_qkv<<<dim3(NQKV / 64, 2048 / 64), 256, 0, stream>>>(x, WqkvT, bq, bk, bv,
                                                             q_buf, k_buf, v_buf);

    attn_kernel<<<dim3(BATCH * G_KV * R_REP * (S_LEN / 64)), 256, 0, stream>>>(
        q_buf, k_buf, v_buf, mask, a_out);

    gemm_o<<<dim3(2048 / 64, 2048 / 64), 256, 0, stream>>>(a_out, WoT, bo, x, out);
}

// Round 6
// 315.989 us; speedup vs baseline: 1.9553x; 1.9553x over previous
//
#include <hip/hip_runtime.h>

typedef unsigned short u16;
typedef unsigned int u32;
typedef __attribute__((ext_vector_type(8))) short bf16x8;
typedef __attribute__((ext_vector_type(4))) float f32x4;

#define HID 2048
#define S_LEN 1024
#define BATCH 2
#define G_KV 8
#define R_REP 4
#define HD 64
#define NQKV 3072  // 2048 q + 512 k + 512 v

__device__ __forceinline__ u16 f2bf(float f) {
    union { u32 u; float ff; } x; x.ff = f;
    u32 u = x.u;
    u += 0x7FFFu + ((u >> 16) & 1u);
    return (u16)(u >> 16);
}

// ------- Transpose+convert: in fp32 [K][N] -> out bf16 [N][K] -------
__global__ __launch_bounds__(256) void transpose_cvt(const float* __restrict__ in,
                                                     u16* __restrict__ out,
                                                     int K, int N) {
    __shared__ float tile[32][33];
    int n0 = blockIdx.x * 32, k0 = blockIdx.y * 32;
    int tx = threadIdx.x, ty = threadIdx.y;
#pragma unroll
    for (int j = 0; j < 4; ++j)
        tile[ty + j * 8][tx] = in[(size_t)(k0 + ty + j * 8) * N + n0 + tx];
    __syncthreads();
#pragma unroll
    for (int j = 0; j < 4; ++j)
        out[(size_t)(n0 + ty + j * 8) * K + k0 + tx] = f2bf(tile[tx][ty + j * 8]);
}

// ------- QKV GEMM: Y = X(fp32) @ W + b -> bf16 q/k/v (V stored TRANSPOSED) -------
__global__ __launch_bounds__(256) void gemm_qkv(const float* __restrict__ X,
                                                const u16* __restrict__ WT,
                                                const float* __restrict__ bq,
                                                const float* __restrict__ bk,
                                                const float* __restrict__ bv,
                                                u16* __restrict__ qb,
                                                u16* __restrict__ kb,
                                                u16* __restrict__ vb) {
    __shared__ __align__(16) u16 As[64 * 40];
    __shared__ __align__(16) u16 Bs[64 * 40];
    int tid = threadIdx.x;
    int w = tid >> 6, lane = tid & 63, quad = lane >> 4, l16 = lane & 15;
    int m0 = blockIdx.y * 64, n0 = blockIdx.x * 64;
    int lr = tid >> 2, lc = (tid & 3) * 8;

    f32x4 acc[4];
#pragma unroll
    for (int i = 0; i < 4; ++i) acc[i] = (f32x4){0.f, 0.f, 0.f, 0.f};

    for (int k0 = 0; k0 < 2048; k0 += 32) {
        const float* xr = &X[(size_t)(m0 + lr) * 2048 + k0 + lc];
        float4 a0 = *(const float4*)xr;
        float4 a1 = *(const float4*)(xr + 4);
        u16 tmp[8] = {f2bf(a0.x), f2bf(a0.y), f2bf(a0.z), f2bf(a0.w),
                      f2bf(a1.x), f2bf(a1.y), f2bf(a1.z), f2bf(a1.w)};
        *(uint4*)&As[lr * 40 + lc] = *(const uint4*)tmp;
        *(uint4*)&Bs[lr * 40 + lc] = *(const uint4*)&WT[(size_t)(n0 + lr) * 2048 + k0 + lc];
        __syncthreads();
        bf16x8 a = *(const bf16x8*)&As[(w * 16 + l16) * 40 + quad * 8];
#pragma unroll
        for (int nt = 0; nt < 4; ++nt) {
            bf16x8 bfr = *(const bf16x8*)&Bs[(nt * 16 + l16) * 40 + quad * 8];
            acc[nt] = __builtin_amdgcn_mfma_f32_16x16x32_bf16(a, bfr, acc[nt], 0, 0, 0);
        }
        __syncthreads();
    }

#pragma unroll
    for (int nt = 0; nt < 4; ++nt) {
        int n = n0 + nt * 16 + l16;
        float bias;
        if (n < 2048) bias = bq[n];
        else if (n < 2560) bias = bk[n - 2048];
        else bias = bv[n - 2560];
#pragma unroll
        for (int reg = 0; reg < 4; ++reg) {
            int m = m0 + w * 16 + quad * 4 + reg;  // C/D: row=quad*4+reg, col=l16
            float val = acc[nt][reg] + bias;
            int b = m >> 10, s = m & 1023;
            u16 bfv = f2bf(val);
            if (n < 2048) {
                int g = n >> 8, r = (n >> 6) & 3, d = n & 63;
                qb[((((size_t)(b * G_KV + g) * R_REP + r) * S_LEN) + s) * HD + d] = bfv;
            } else if (n < 2560) {
                int n2 = n - 2048, g = n2 >> 6, d = n2 & 63;
                kb[(((size_t)(b * G_KV + g) * S_LEN) + s) * HD + d] = bfv;
            } else {
                int n2 = n - 2560, g = n2 >> 6, d = n2 & 63;
                // V transposed: [b][g][d][s] so attn PV B-frags are contiguous
                vb[(((size_t)(b * G_KV + g) * HD + d) * S_LEN) + s] = bfv;
            }
        }
    }
}

// ------- Attention: flash-style with MFMA QK^T and PV; l via shfl reduction -------
// grid = B*G*R*(S/64) = 1024 blocks, 256 threads (4 waves; wave = 16-row Q strip).
__global__ __launch_bounds__(256) void attn_mfma(const u16* __restrict__ qbuf,
                                                 const u16* __restrict__ kbuf,
                                                 const u16* __restrict__ vtbuf,
                                                 const float* __restrict__ mask,
                                                 u16* __restrict__ aout) {
    __shared__ __align__(16) u16 Ks[64 * 72];   // [key][dim]
    __shared__ __align__(16) u16 Vs[64 * 72];   // [dim][key] (transposed V)
    __shared__ __align__(16) float Ms[64 * 68]; // [q][key], pre-scaled by 0.125
    __shared__ __align__(16) u16 Ps[64 * 72];   // [q][key] bf16 P round-trip

    int bid = blockIdx.x;
    int qblk = bid & 15, r = (bid >> 4) & 3, g = (bid >> 6) & 7, b = bid >> 9;
    int tid = threadIdx.x;
    int w = tid >> 6, lane = tid & 63, quad = lane >> 4, l16 = lane & 15;
    int s0 = qblk * 64;

    // Q A-fragments: m = w*16 + l16, k = quad*8+j (frag0: dims 0..31, frag1: 32..63)
    const u16* qrow = qbuf +
        ((((size_t)(b * G_KV + g) * R_REP + r) * S_LEN) + s0 + w * 16 + l16) * HD;
    bf16x8 qf0 = *(const bf16x8*)(qrow + quad * 8);
    bf16x8 qf1 = *(const bf16x8*)(qrow + 32 + quad * 8);

    f32x4 o_acc[4];
#pragma unroll
    for (int i = 0; i < 4; ++i) o_acc[i] = (f32x4){0.f, 0.f, 0.f, 0.f};
    float l_tot[4] = {0.f, 0.f, 0.f, 0.f};

    const u16* kbase  = kbuf  + (size_t)(b * G_KV + g) * S_LEN * HD;
    const u16* vtbase = vtbuf + (size_t)(b * G_KV + g) * HD * S_LEN;
    const float* mbase = mask + ((size_t)b * S_LEN + s0) * S_LEN;

    int srow = tid >> 2, sc = (tid & 3) * 16;
    int prow = w * 16 + quad * 4;  // this lane's C/D row base (q row within block)

    for (int kt = 0; kt < 16; ++kt) {
        __syncthreads();
        // ---- stage K tile, Vt tile, mask tile ----
        {
            const u16* kr = kbase + (size_t)(kt * 64 + srow) * HD + sc;
            *(uint4*)&Ks[srow * 72 + sc]     = *(const uint4*)kr;
            *(uint4*)&Ks[srow * 72 + sc + 8] = *(const uint4*)(kr + 8);
            const u16* vr = vtbase + (size_t)srow * S_LEN + kt * 64 + sc;
            *(uint4*)&Vs[srow * 72 + sc]     = *(const uint4*)vr;
            *(uint4*)&Vs[srow * 72 + sc + 8] = *(const uint4*)(vr + 8);
            const float* mr = mbase + (size_t)srow * S_LEN + kt * 64 + sc;
#pragma unroll
            for (int i = 0; i < 4; ++i) {
                float4 m4 = *(const float4*)(mr + i * 4);
                Ms[srow * 68 + sc + i * 4 + 0] = m4.x * 0.125f;
                Ms[srow * 68 + sc + i * 4 + 1] = m4.y * 0.125f;
                Ms[srow * 68 + sc + i * 4 + 2] = m4.z * 0.125f;
                Ms[srow * 68 + sc + i * 4 + 3] = m4.w * 0.125f;
            }
        }
        __syncthreads();

        // ---- QK^T: 4 key n-tiles x 2 k-frags ----
        f32x4 p[4];
#pragma unroll
        for (int nt = 0; nt < 4; ++nt) {
            bf16x8 kf0 = *(const bf16x8*)&Ks[(nt * 16 + l16) * 72 + quad * 8];
            bf16x8 kf1 = *(const bf16x8*)&Ks[(nt * 16 + l16) * 72 + 32 + quad * 8];
            f32x4 z = (f32x4){0.f, 0.f, 0.f, 0.f};
            z = __builtin_amdgcn_mfma_f32_16x16x32_bf16(qf0, kf0, z, 0, 0, 0);
            p[nt] = __builtin_amdgcn_mfma_f32_16x16x32_bf16(qf1, kf1, z, 0, 0, 0);
        }

        // ---- mask*scale, exp, accumulate l partials, write P strip ----
        float part[4] = {0.f, 0.f, 0.f, 0.f};
#pragma unroll
        for (int nt = 0; nt < 4; ++nt) {
#pragma unroll
            for (int reg = 0; reg < 4; ++reg) {
                int qr = prow + reg;
                float e = __expf(p[nt][reg] * Ms[qr * 68 + nt * 16 + l16]);
                part[reg] += e;
                Ps[qr * 72 + nt * 16 + l16] = f2bf(e);
            }
        }
        __syncthreads();  // P strip visible before fragment reads

        // ---- l reduction across the 16 columns (within quad lanes) ----
#pragma unroll
        for (int reg = 0; reg < 4; ++reg) {
            float v = part[reg];
            v += __shfl_xor(v, 1);
            v += __shfl_xor(v, 2);
            v += __shfl_xor(v, 4);
            v += __shfl_xor(v, 8);
            l_tot[reg] += v;   // every lane now holds l for row prow+reg
        }

        // ---- P A-frags and PV: 4 dim n-tiles x 2 k-frags ----
        bf16x8 pf0 = *(const bf16x8*)&Ps[(w * 16 + l16) * 72 + quad * 8];
        bf16x8 pf1 = *(const bf16x8*)&Ps[(w * 16 + l16) * 72 + 32 + quad * 8];
#pragma unroll
        for (int nt = 0; nt < 4; ++nt) {
            bf16x8 vf0 = *(const bf16x8*)&Vs[(nt * 16 + l16) * 72 + quad * 8];
            bf16x8 vf1 = *(const bf16x8*)&Vs[(nt * 16 + l16) * 72 + 32 + quad * 8];
            o_acc[nt] = __builtin_amdgcn_mfma_f32_16x16x32_bf16(pf0, vf0, o_acc[nt], 0, 0, 0);
            o_acc[nt] = __builtin_amdgcn_mfma_f32_16x16x32_bf16(pf1, vf1, o_acc[nt], 0, 0, 0);
        }
    }

    // ---- epilogue: normalize, store bf16 to a_out [B*S][HID] ----
#pragma unroll
    for (int reg = 0; reg < 4; ++reg) {
        int row = prow + reg;
        float inv = 1.0f / l_tot[reg];
        int sidx = s0 + row;
        u16* dst = aout + ((size_t)(b * S_LEN + sidx)) * HID + (g * R_REP + r) * HD;
#pragma unroll
        for (int nt = 0; nt < 4; ++nt)
            dst[nt * 16 + l16] = f2bf(o_acc[nt][reg] * inv);
    }
}

// ------- Output GEMM: out = A(bf16) @ Wo + bo + x(fp32), out FP32 -------
__global__ __launch_bounds__(256) void gemm_o(const u16* __restrict__ A,
                                              const u16* __restrict__ WT,
                                              const float* __restrict__ bo,
                                              const float* __restrict__ Xres,
                                              float* __restrict__ out) {
    __shared__ __align__(16) u16 As[64 * 40];
    __shared__ __align__(16) u16 Bs[64 * 40];
    int tid = threadIdx.x;
    int w = tid >> 6, lane = tid & 63, quad = lane >> 4, l16 = lane & 15;
    int m0 = blockIdx.y * 64, n0 = blockIdx.x * 64;
    int lr = tid >> 2, lc = (tid & 3) * 8;

    f32x4 acc[4];
#pragma unroll
    for (int i = 0; i < 4; ++i) acc[i] = (f32x4){0.f, 0.f, 0.f, 0.f};

    for (int k0 = 0; k0 < 2048; k0 += 32) {
        *(uint4*)&As[lr * 40 + lc] = *(const uint4*)&A[(size_t)(m0 + lr) * 2048 + k0 + lc];
        *(uint4*)&Bs[lr * 40 + lc] = *(const uint4*)&WT[(size_t)(n0 + lr) * 2048 + k0 + lc];
        __syncthreads();
        bf16x8 a = *(const bf16x8*)&As[(w * 16 + l16) * 40 + quad * 8];
#pragma unroll
        for (int nt = 0; nt < 4; ++nt) {
            bf16x8 bfr = *(const bf16x8*)&Bs[(nt * 16 + l16) * 40 + quad * 8];
            acc[nt] = __builtin_amdgcn_mfma_f32_16x16x32_bf16(a, bfr, acc[nt], 0, 0, 0);
        }
        __syncthreads();
    }

#pragma unroll
    for (int nt = 0; nt < 4; ++nt) {
        int n = n0 + nt * 16 + l16;
        float bias = bo[n];
#pragma unroll
        for (int reg = 0; reg < 4; ++reg) {
            int m = m0 + w * 16 + quad * 4 + reg;
            float val = acc[nt][reg] + bias + Xres[(size_t)m * 2048 + n];
            out[(size_t)m * 2048 + n] = val;   // FP32 store — d_out is float*
        }
    }
}

extern "C" void kernel_launch(void* const* d_in, const int* in_sizes, int n_in,
                              void* d_out, int out_size, void* d_ws, size_t ws_size,
                              hipStream_t stream) {
    const float* x    = (const float*)d_in[0];
    const float* mask = (const float*)d_in[1];
    const float* Wq   = (const float*)d_in[2];
    const float* bq   = (const float*)d_in[3];
    const float* Wk   = (const float*)d_in[4];
    const float* bk   = (const float*)d_in[5];
    const float* Wv   = (const float*)d_in[6];
    const float* bv   = (const float*)d_in[7];
    const float* Wo   = (const float*)d_in[8];
    const float* bo   = (const float*)d_in[9];
    float* out = (float*)d_out;

    u16* ws = (u16*)d_ws;
    size_t off = 0;
    u16* WqkvT = ws + off; off += (size_t)NQKV * 2048;
    u16* WoT   = ws + off; off += (size_t)2048 * 2048;
    u16* q_buf = ws + off; off += (size_t)BATCH * G_KV * R_REP * S_LEN * HD;
    u16* k_buf = ws + off; off += (size_t)BATCH * G_KV * S_LEN * HD;
    u16* v_buf = ws + off; off += (size_t)BATCH * G_KV * S_LEN * HD;  // transposed [b][g][d][s]
    u16* a_out = ws + off; off += (size_t)2048 * 2048;                // ~42 MB total

    dim3 tb(32, 8);
    transpose_cvt<<<dim3(64, 64), tb, 0, stream>>>(Wq, WqkvT, 2048, 2048);
    transpose_cvt<<<dim3(16, 64), tb, 0, stream>>>(Wk, WqkvT + (size_t)2048 * 2048, 2048, 512);
    transpose_cvt<<<dim3(16, 64), tb, 0, stream>>>(Wv, WqkvT + (size_t)2560 * 2048, 2048, 512);
    transpose_cvt<<<dim3(64, 64), tb, 0, stream>>>(Wo, WoT, 2048, 2048);

    gemm_qkv<<<dim3(NQKV / 64, 2048 / 64), 256, 0, stream>>>(x, WqkvT, bq, bk, bv,
                                                             q_buf, k_buf, v_buf);

    attn_mfma<<<dim3(BATCH * G_KV * R_REP * (S_LEN / 64)), 256, 0, stream>>>(
        q_buf, k_buf, v_buf, mask, a_out);

    gemm_o<<<dim3(2048 / 64, 2048 / 64), 256, 0, stream>>>(a_out, WoT, bo, x, out);
}

// Round 7
// 284.742 us; speedup vs baseline: 2.1699x; 1.1097x over previous
//
#include <hip/hip_runtime.h>

typedef unsigned short u16;
typedef unsigned int u32;
typedef __attribute__((ext_vector_type(8))) short bf16x8;
typedef __attribute__((ext_vector_type(4))) float f32x4;

#define HID 2048
#define S_LEN 1024
#define BATCH 2
#define G_KV 8
#define R_REP 4
#define HD 64
#define NQKV 3072  // 2048 q + 512 k + 512 v

__device__ __forceinline__ u16 f2bf(float f) {
    union { u32 u; float ff; } x; x.ff = f;
    u32 u = x.u;
    u += 0x7FFFu + ((u >> 16) & 1u);
    return (u16)(u >> 16);
}

__device__ __forceinline__ void gload_lds16(const void* g, void* l) {
    // async global->LDS, 16 B per lane; LDS dst = wave-uniform base + lane*16
    __builtin_amdgcn_global_load_lds((const __attribute__((address_space(1))) void*)g,
                                     (__attribute__((address_space(3))) void*)l,
                                     16, 0, 0);
}

// ------- x fp32 -> bf16 (one-shot) -------
__global__ __launch_bounds__(256) void cvt_x(const float* __restrict__ in,
                                             u16* __restrict__ out) {
    int i = (blockIdx.x * 256 + threadIdx.x) * 8;
    float4 a = *(const float4*)(in + i);
    float4 b = *(const float4*)(in + i + 4);
    u16 t[8] = {f2bf(a.x), f2bf(a.y), f2bf(a.z), f2bf(a.w),
                f2bf(b.x), f2bf(b.y), f2bf(b.z), f2bf(b.w)};
    *(uint4*)(out + i) = *(const uint4*)t;
}

// ------- Transpose+convert: in fp32 [K][N] -> out bf16 [N][K] -------
__global__ __launch_bounds__(256) void transpose_cvt(const float* __restrict__ in,
                                                     u16* __restrict__ out,
                                                     int K, int N) {
    __shared__ float tile[32][33];
    int n0 = blockIdx.x * 32, k0 = blockIdx.y * 32;
    int tx = threadIdx.x, ty = threadIdx.y;
#pragma unroll
    for (int j = 0; j < 4; ++j)
        tile[ty + j * 8][tx] = in[(size_t)(k0 + ty + j * 8) * N + n0 + tx];
    __syncthreads();
#pragma unroll
    for (int j = 0; j < 4; ++j)
        out[(size_t)(n0 + ty + j * 8) * K + k0 + tx] = f2bf(tile[tx][ty + j * 8]);
}

// ------- QKV GEMM (m97-style): Y = Xb(bf16) @ W + b -> bf16 q/k/v (V TRANSPOSED) -------
// A: Xb [2048][2048] bf16 row-major; B: WT [3072][2048] bf16 (B^T layout).
// BM=BN=128, BK=32, 256 thr = 4 waves in 2x2; wave does 64x64 (4x4 16x16 tiles).
__global__ __launch_bounds__(256) void gemm_qkv(const u16* __restrict__ Xb,
                                                const u16* __restrict__ WT,
                                                const float* __restrict__ bq,
                                                const float* __restrict__ bk,
                                                const float* __restrict__ bv,
                                                u16* __restrict__ qb,
                                                u16* __restrict__ kb,
                                                u16* __restrict__ vb) {
    __shared__ __align__(16) u16 As[128 * 32];
    __shared__ __align__(16) u16 Bs[128 * 32];
    int tid = threadIdx.x;
    int w = tid >> 6, lane = tid & 63, quad = lane >> 4, l16 = lane & 15;
    int m0 = blockIdx.y * 128, n0 = blockIdx.x * 128;
    int wr = (w >> 1) * 64, wc = (w & 1) * 64;
    int srow = lane >> 2, scol = (lane & 3) * 8;   // staging: row within 16-row strip, k-offset

    f32x4 acc[4][4];
#pragma unroll
    for (int i = 0; i < 4; ++i)
#pragma unroll
        for (int j = 0; j < 4; ++j) acc[i][j] = (f32x4){0.f, 0.f, 0.f, 0.f};

    for (int k0 = 0; k0 < 2048; k0 += 32) {
#pragma unroll
        for (int c = 0; c < 2; ++c) {
            int row = c * 64 + w * 16 + srow;
            gload_lds16(&Xb[(size_t)(m0 + row) * 2048 + k0 + scol], &As[(c * 64 + w * 16) * 32]);
            gload_lds16(&WT[(size_t)(n0 + row) * 2048 + k0 + scol], &Bs[(c * 64 + w * 16) * 32]);
        }
        __syncthreads();
        bf16x8 af[4], bfr[4];
#pragma unroll
        for (int mt = 0; mt < 4; ++mt)
            af[mt] = *(const bf16x8*)&As[(wr + mt * 16 + l16) * 32 + quad * 8];
#pragma unroll
        for (int nt = 0; nt < 4; ++nt)
            bfr[nt] = *(const bf16x8*)&Bs[(wc + nt * 16 + l16) * 32 + quad * 8];
#pragma unroll
        for (int mt = 0; mt < 4; ++mt)
#pragma unroll
            for (int nt = 0; nt < 4; ++nt)
                acc[mt][nt] = __builtin_amdgcn_mfma_f32_16x16x32_bf16(af[mt], bfr[nt], acc[mt][nt], 0, 0, 0);
        __syncthreads();
    }

#pragma unroll
    for (int nt = 0; nt < 4; ++nt) {
        int n = n0 + wc + nt * 16 + l16;
        float bias;
        if (n < 2048) bias = bq[n];
        else if (n < 2560) bias = bk[n - 2048];
        else bias = bv[n - 2560];
#pragma unroll
        for (int mt = 0; mt < 4; ++mt) {
#pragma unroll
            for (int reg = 0; reg < 4; ++reg) {
                int m = m0 + wr + mt * 16 + quad * 4 + reg;
                float val = acc[mt][nt][reg] + bias;
                int b = m >> 10, s = m & 1023;
                u16 bfv = f2bf(val);
                if (n < 2048) {
                    int g = n >> 8, r = (n >> 6) & 3, d = n & 63;
                    qb[((((size_t)(b * G_KV + g) * R_REP + r) * S_LEN) + s) * HD + d] = bfv;
                } else if (n < 2560) {
                    int n2 = n - 2048, g = n2 >> 6, d = n2 & 63;
                    kb[(((size_t)(b * G_KV + g) * S_LEN) + s) * HD + d] = bfv;
                } else {
                    int n2 = n - 2560, g = n2 >> 6, d = n2 & 63;
                    vb[(((size_t)(b * G_KV + g) * HD + d) * S_LEN) + s] = bfv;  // V^T
                }
            }
        }
    }
}

// ------- Attention: flash-style with MFMA QK^T and PV; l via shfl reduction -------
__global__ __launch_bounds__(256) void attn_mfma(const u16* __restrict__ qbuf,
                                                 const u16* __restrict__ kbuf,
                                                 const u16* __restrict__ vtbuf,
                                                 const float* __restrict__ mask,
                                                 u16* __restrict__ aout) {
    __shared__ __align__(16) u16 Ks[64 * 72];   // [key][dim]
    __shared__ __align__(16) u16 Vs[64 * 72];   // [dim][key] (transposed V)
    __shared__ __align__(16) float Ms[64 * 68]; // [q][key], pre-scaled by 0.125
    __shared__ __align__(16) u16 Ps[64 * 72];   // [q][key] bf16 P round-trip

    int bid = blockIdx.x;
    int qblk = bid & 15, r = (bid >> 4) & 3, g = (bid >> 6) & 7, b = bid >> 9;
    int tid = threadIdx.x;
    int w = tid >> 6, lane = tid & 63, quad = lane >> 4, l16 = lane & 15;
    int s0 = qblk * 64;

    const u16* qrow = qbuf +
        ((((size_t)(b * G_KV + g) * R_REP + r) * S_LEN) + s0 + w * 16 + l16) * HD;
    bf16x8 qf0 = *(const bf16x8*)(qrow + quad * 8);
    bf16x8 qf1 = *(const bf16x8*)(qrow + 32 + quad * 8);

    f32x4 o_acc[4];
#pragma unroll
    for (int i = 0; i < 4; ++i) o_acc[i] = (f32x4){0.f, 0.f, 0.f, 0.f};
    float l_tot[4] = {0.f, 0.f, 0.f, 0.f};

    const u16* kbase  = kbuf  + (size_t)(b * G_KV + g) * S_LEN * HD;
    const u16* vtbase = vtbuf + (size_t)(b * G_KV + g) * HD * S_LEN;
    const float* mbase = mask + ((size_t)b * S_LEN + s0) * S_LEN;

    int srow = tid >> 2, sc = (tid & 3) * 16;
    int prow = w * 16 + quad * 4;

    for (int kt = 0; kt < 16; ++kt) {
        __syncthreads();
        {
            const u16* kr = kbase + (size_t)(kt * 64 + srow) * HD + sc;
            *(uint4*)&Ks[srow * 72 + sc]     = *(const uint4*)kr;
            *(uint4*)&Ks[srow * 72 + sc + 8] = *(const uint4*)(kr + 8);
            const u16* vr = vtbase + (size_t)srow * S_LEN + kt * 64 + sc;
            *(uint4*)&Vs[srow * 72 + sc]     = *(const uint4*)vr;
            *(uint4*)&Vs[srow * 72 + sc + 8] = *(const uint4*)(vr + 8);
            const float* mr = mbase + (size_t)srow * S_LEN + kt * 64 + sc;
#pragma unroll
            for (int i = 0; i < 4; ++i) {
                float4 m4 = *(const float4*)(mr + i * 4);
                Ms[srow * 68 + sc + i * 4 + 0] = m4.x * 0.125f;
                Ms[srow * 68 + sc + i * 4 + 1] = m4.y * 0.125f;
                Ms[srow * 68 + sc + i * 4 + 2] = m4.z * 0.125f;
                Ms[srow * 68 + sc + i * 4 + 3] = m4.w * 0.125f;
            }
        }
        __syncthreads();

        f32x4 p[4];
#pragma unroll
        for (int nt = 0; nt < 4; ++nt) {
            bf16x8 kf0 = *(const bf16x8*)&Ks[(nt * 16 + l16) * 72 + quad * 8];
            bf16x8 kf1 = *(const bf16x8*)&Ks[(nt * 16 + l16) * 72 + 32 + quad * 8];
            f32x4 z = (f32x4){0.f, 0.f, 0.f, 0.f};
            z = __builtin_amdgcn_mfma_f32_16x16x32_bf16(qf0, kf0, z, 0, 0, 0);
            p[nt] = __builtin_amdgcn_mfma_f32_16x16x32_bf16(qf1, kf1, z, 0, 0, 0);
        }

        float part[4] = {0.f, 0.f, 0.f, 0.f};
#pragma unroll
        for (int nt = 0; nt < 4; ++nt) {
#pragma unroll
            for (int reg = 0; reg < 4; ++reg) {
                int qr = prow + reg;
                float e = __expf(p[nt][reg] * Ms[qr * 68 + nt * 16 + l16]);
                part[reg] += e;
                Ps[qr * 72 + nt * 16 + l16] = f2bf(e);
            }
        }
        __syncthreads();

#pragma unroll
        for (int reg = 0; reg < 4; ++reg) {
            float v = part[reg];
            v += __shfl_xor(v, 1);
            v += __shfl_xor(v, 2);
            v += __shfl_xor(v, 4);
            v += __shfl_xor(v, 8);
            l_tot[reg] += v;
        }

        bf16x8 pf0 = *(const bf16x8*)&Ps[(w * 16 + l16) * 72 + quad * 8];
        bf16x8 pf1 = *(const bf16x8*)&Ps[(w * 16 + l16) * 72 + 32 + quad * 8];
#pragma unroll
        for (int nt = 0; nt < 4; ++nt) {
            bf16x8 vf0 = *(const bf16x8*)&Vs[(nt * 16 + l16) * 72 + quad * 8];
            bf16x8 vf1 = *(const bf16x8*)&Vs[(nt * 16 + l16) * 72 + 32 + quad * 8];
            o_acc[nt] = __builtin_amdgcn_mfma_f32_16x16x32_bf16(pf0, vf0, o_acc[nt], 0, 0, 0);
            o_acc[nt] = __builtin_amdgcn_mfma_f32_16x16x32_bf16(pf1, vf1, o_acc[nt], 0, 0, 0);
        }
    }

#pragma unroll
    for (int reg = 0; reg < 4; ++reg) {
        int row = prow + reg;
        float inv = 1.0f / l_tot[reg];
        int sidx = s0 + row;
        u16* dst = aout + ((size_t)(b * S_LEN + sidx)) * HID + (g * R_REP + r) * HD;
#pragma unroll
        for (int nt = 0; nt < 4; ++nt)
            dst[nt * 16 + l16] = f2bf(o_acc[nt][reg] * inv);
    }
}

// ------- Output GEMM (m97-style): out = A(bf16) @ Wo + bo + x(fp32), fp32 out -------
__global__ __launch_bounds__(256) void gemm_o(const u16* __restrict__ A,
                                              const u16* __restrict__ WT,
                                              const float* __restrict__ bo,
                                              const float* __restrict__ Xres,
                                              float* __restrict__ out) {
    __shared__ __align__(16) u16 As[128 * 32];
    __shared__ __align__(16) u16 Bs[128 * 32];
    int tid = threadIdx.x;
    int w = tid >> 6, lane = tid & 63, quad = lane >> 4, l16 = lane & 15;
    int m0 = blockIdx.y * 128, n0 = blockIdx.x * 128;
    int wr = (w >> 1) * 64, wc = (w & 1) * 64;
    int srow = lane >> 2, scol = (lane & 3) * 8;

    f32x4 acc[4][4];
#pragma unroll
    for (int i = 0; i < 4; ++i)
#pragma unroll
        for (int j = 0; j < 4; ++j) acc[i][j] = (f32x4){0.f, 0.f, 0.f, 0.f};

    for (int k0 = 0; k0 < 2048; k0 += 32) {
#pragma unroll
        for (int c = 0; c < 2; ++c) {
            int row = c * 64 + w * 16 + srow;
            gload_lds16(&A[(size_t)(m0 + row) * 2048 + k0 + scol],  &As[(c * 64 + w * 16) * 32]);
            gload_lds16(&WT[(size_t)(n0 + row) * 2048 + k0 + scol], &Bs[(c * 64 + w * 16) * 32]);
        }
        __syncthreads();
        bf16x8 af[4], bfr[4];
#pragma unroll
        for (int mt = 0; mt < 4; ++mt)
            af[mt] = *(const bf16x8*)&As[(wr + mt * 16 + l16) * 32 + quad * 8];
#pragma unroll
        for (int nt = 0; nt < 4; ++nt)
            bfr[nt] = *(const bf16x8*)&Bs[(wc + nt * 16 + l16) * 32 + quad * 8];
#pragma unroll
        for (int mt = 0; mt < 4; ++mt)
#pragma unroll
            for (int nt = 0; nt < 4; ++nt)
                acc[mt][nt] = __builtin_amdgcn_mfma_f32_16x16x32_bf16(af[mt], bfr[nt], acc[mt][nt], 0, 0, 0);
        __syncthreads();
    }

#pragma unroll
    for (int nt = 0; nt < 4; ++nt) {
        int n = n0 + wc + nt * 16 + l16;
        float bias = bo[n];
#pragma unroll
        for (int mt = 0; mt < 4; ++mt) {
#pragma unroll
            for (int reg = 0; reg < 4; ++reg) {
                int m = m0 + wr + mt * 16 + quad * 4 + reg;
                out[(size_t)m * 2048 + n] = acc[mt][nt][reg] + bias + Xres[(size_t)m * 2048 + n];
            }
        }
    }
}

extern "C" void kernel_launch(void* const* d_in, const int* in_sizes, int n_in,
                              void* d_out, int out_size, void* d_ws, size_t ws_size,
                              hipStream_t stream) {
    const float* x    = (const float*)d_in[0];
    const float* mask = (const float*)d_in[1];
    const float* Wq   = (const float*)d_in[2];
    const float* bq   = (const float*)d_in[3];
    const float* Wk   = (const float*)d_in[4];
    const float* bk   = (const float*)d_in[5];
    const float* Wv   = (const float*)d_in[6];
    const float* bv   = (const float*)d_in[7];
    const float* Wo   = (const float*)d_in[8];
    const float* bo   = (const float*)d_in[9];
    float* out = (float*)d_out;

    u16* ws = (u16*)d_ws;
    size_t off = 0;
    u16* WqkvT = ws + off; off += (size_t)NQKV * 2048;
    u16* WoT   = ws + off; off += (size_t)2048 * 2048;
    u16* q_buf = ws + off; off += (size_t)BATCH * G_KV * R_REP * S_LEN * HD;
    u16* k_buf = ws + off; off += (size_t)BATCH * G_KV * S_LEN * HD;
    u16* v_buf = ws + off; off += (size_t)BATCH * G_KV * S_LEN * HD;  // transposed [b][g][d][s]
    u16* a_out = ws + off; off += (size_t)2048 * 2048;                // ~42 MB total
    u16* Xb    = a_out;  // alias: Xb consumed by gemm_qkv before attn writes a_out

    cvt_x<<<dim3(2048 * 2048 / (256 * 8)), 256, 0, stream>>>(x, Xb);

    dim3 tb(32, 8);
    transpose_cvt<<<dim3(64, 64), tb, 0, stream>>>(Wq, WqkvT, 2048, 2048);
    transpose_cvt<<<dim3(16, 64), tb, 0, stream>>>(Wk, WqkvT + (size_t)2048 * 2048, 2048, 512);
    transpose_cvt<<<dim3(16, 64), tb, 0, stream>>>(Wv, WqkvT + (size_t)2560 * 2048, 2048, 512);
    transpose_cvt<<<dim3(64, 64), tb, 0, stream>>>(Wo, WoT, 2048, 2048);

    gemm_qkv<<<dim3(NQKV / 128, 2048 / 128), 256, 0, stream>>>(Xb, WqkvT, bq, bk, bv,
                                                               q_buf, k_buf, v_buf);

    attn_mfma<<<dim3(BATCH * G_KV * R_REP * (S_LEN / 64)), 256, 0, stream>>>(
        q_buf, k_buf, v_buf, mask, a_out);

    gemm_o<<<dim3(2048 / 128, 2048 / 128), 256, 0, stream>>>(a_out, WoT, bo, x, out);
}

// Round 8
// 273.026 us; speedup vs baseline: 2.2630x; 1.0429x over previous
//
#include <hip/hip_runtime.h>

typedef unsigned short u16;
typedef unsigned int u32;
typedef __attribute__((ext_vector_type(8))) short bf16x8;
typedef __attribute__((ext_vector_type(4))) float f32x4;

#define HID 2048
#define S_LEN 1024
#define BATCH 2
#define G_KV 8
#define R_REP 4
#define HD 64
#define NQKV 3072  // 2048 q + 512 k + 512 v

__device__ __forceinline__ u16 f2bf(float f) {
    union { u32 u; float ff; } x; x.ff = f;
    u32 u = x.u;
    u += 0x7FFFu + ((u >> 16) & 1u);
    return (u16)(u >> 16);
}
__device__ __forceinline__ float bf2f(u16 v) {
    union { u32 u; float f; } x; x.u = ((u32)v) << 16; return x.f;
}

__device__ __forceinline__ void gload_lds16(const void* g, void* l) {
    __builtin_amdgcn_global_load_lds((const __attribute__((address_space(1))) void*)g,
                                     (__attribute__((address_space(3))) void*)l,
                                     16, 0, 0);
}

// ------- fp32 -> bf16 bulk convert (x and mask) -------
__global__ __launch_bounds__(256) void cvt_x(const float* __restrict__ in,
                                             u16* __restrict__ out) {
    int i = (blockIdx.x * 256 + threadIdx.x) * 8;
    float4 a = *(const float4*)(in + i);
    float4 b = *(const float4*)(in + i + 4);
    u16 t[8] = {f2bf(a.x), f2bf(a.y), f2bf(a.z), f2bf(a.w),
                f2bf(b.x), f2bf(b.y), f2bf(b.z), f2bf(b.w)};
    *(uint4*)(out + i) = *(const uint4*)t;
}

// ------- Transpose+convert: in fp32 [K][N] -> out bf16 [N][K] -------
__global__ __launch_bounds__(256) void transpose_cvt(const float* __restrict__ in,
                                                     u16* __restrict__ out,
                                                     int K, int N) {
    __shared__ float tile[32][33];
    int n0 = blockIdx.x * 32, k0 = blockIdx.y * 32;
    int tx = threadIdx.x, ty = threadIdx.y;
#pragma unroll
    for (int j = 0; j < 4; ++j)
        tile[ty + j * 8][tx] = in[(size_t)(k0 + ty + j * 8) * N + n0 + tx];
    __syncthreads();
#pragma unroll
    for (int j = 0; j < 4; ++j)
        out[(size_t)(n0 + ty + j * 8) * K + k0 + tx] = f2bf(tile[tx][ty + j * 8]);
}

// ------- QKV GEMM (m97-style): q pre-scaled by 0.125; V stored transposed -------
__global__ __launch_bounds__(256) void gemm_qkv(const u16* __restrict__ Xb,
                                                const u16* __restrict__ WT,
                                                const float* __restrict__ bq,
                                                const float* __restrict__ bk,
                                                const float* __restrict__ bv,
                                                u16* __restrict__ qb,
                                                u16* __restrict__ kb,
                                                u16* __restrict__ vb) {
    __shared__ __align__(16) u16 As[128 * 32];
    __shared__ __align__(16) u16 Bs[128 * 32];
    int tid = threadIdx.x;
    int w = tid >> 6, lane = tid & 63, quad = lane >> 4, l16 = lane & 15;
    int m0 = blockIdx.y * 128, n0 = blockIdx.x * 128;
    int wr = (w >> 1) * 64, wc = (w & 1) * 64;
    int srow = lane >> 2, scol = (lane & 3) * 8;

    f32x4 acc[4][4];
#pragma unroll
    for (int i = 0; i < 4; ++i)
#pragma unroll
        for (int j = 0; j < 4; ++j) acc[i][j] = (f32x4){0.f, 0.f, 0.f, 0.f};

    for (int k0 = 0; k0 < 2048; k0 += 32) {
#pragma unroll
        for (int c = 0; c < 2; ++c) {
            int row = c * 64 + w * 16 + srow;
            gload_lds16(&Xb[(size_t)(m0 + row) * 2048 + k0 + scol], &As[(c * 64 + w * 16) * 32]);
            gload_lds16(&WT[(size_t)(n0 + row) * 2048 + k0 + scol], &Bs[(c * 64 + w * 16) * 32]);
        }
        __syncthreads();
        bf16x8 af[4], bfr[4];
#pragma unroll
        for (int mt = 0; mt < 4; ++mt)
            af[mt] = *(const bf16x8*)&As[(wr + mt * 16 + l16) * 32 + quad * 8];
#pragma unroll
        for (int nt = 0; nt < 4; ++nt)
            bfr[nt] = *(const bf16x8*)&Bs[(wc + nt * 16 + l16) * 32 + quad * 8];
#pragma unroll
        for (int mt = 0; mt < 4; ++mt)
#pragma unroll
            for (int nt = 0; nt < 4; ++nt)
                acc[mt][nt] = __builtin_amdgcn_mfma_f32_16x16x32_bf16(af[mt], bfr[nt], acc[mt][nt], 0, 0, 0);
        __syncthreads();
    }

#pragma unroll
    for (int nt = 0; nt < 4; ++nt) {
        int n = n0 + wc + nt * 16 + l16;
        float bias;
        if (n < 2048) bias = bq[n];
        else if (n < 2560) bias = bk[n - 2048];
        else bias = bv[n - 2560];
#pragma unroll
        for (int mt = 0; mt < 4; ++mt) {
#pragma unroll
            for (int reg = 0; reg < 4; ++reg) {
                int m = m0 + wr + mt * 16 + quad * 4 + reg;
                float val = acc[mt][nt][reg] + bias;
                int b = m >> 10, s = m & 1023;
                if (n < 2048) {
                    int g = n >> 8, r = (n >> 6) & 3, d = n & 63;
                    // q pre-scaled by 1/sqrt(HD) (exact pow2)
                    qb[((((size_t)(b * G_KV + g) * R_REP + r) * S_LEN) + s) * HD + d] = f2bf(val * 0.125f);
                } else if (n < 2560) {
                    int n2 = n - 2048, g = n2 >> 6, d = n2 & 63;
                    kb[(((size_t)(b * G_KV + g) * S_LEN) + s) * HD + d] = f2bf(val);
                } else {
                    int n2 = n - 2560, g = n2 >> 6, d = n2 & 63;
                    vb[(((size_t)(b * G_KV + g) * HD + d) * S_LEN) + s] = f2bf(val);  // V^T
                }
            }
        }
    }
}

// ------- Attention: MFMA flash, bf16 mask, register-prefetch pipeline -------
// grid = 1024 blocks, 256 threads; XCD-swizzled so each XCD owns 2 (b,g) pairs.
__global__ __launch_bounds__(256) void attn_mfma(const u16* __restrict__ qbuf,
                                                 const u16* __restrict__ kbuf,
                                                 const u16* __restrict__ vtbuf,
                                                 const u16* __restrict__ mask_bf,
                                                 u16* __restrict__ aout) {
    __shared__ __align__(16) u16 Ks[64 * 72];   // [key][dim]
    __shared__ __align__(16) u16 Vs[64 * 72];   // [dim][key]
    __shared__ __align__(16) u16 Ms[64 * 72];   // [q][key] bf16
    __shared__ __align__(16) u16 Ps[64 * 72];   // [q][key] bf16

    int d = blockIdx.x;
    int xcd = d & 7, j = d >> 3;
    int pr = xcd * 2 + (j >> 6);          // (b,g) pair 0..15
    int r = (j >> 4) & 3, qblk = j & 15;
    int b = pr >> 3, g = pr & 7;

    int tid = threadIdx.x;
    int w = tid >> 6, lane = tid & 63, quad = lane >> 4, l16 = lane & 15;
    int s0 = qblk * 64;

    const u16* qrow = qbuf +
        ((((size_t)(b * G_KV + g) * R_REP + r) * S_LEN) + s0 + w * 16 + l16) * HD;
    bf16x8 qf0 = *(const bf16x8*)(qrow + quad * 8);
    bf16x8 qf1 = *(const bf16x8*)(qrow + 32 + quad * 8);

    f32x4 o_acc[4];
#pragma unroll
    for (int i = 0; i < 4; ++i) o_acc[i] = (f32x4){0.f, 0.f, 0.f, 0.f};
    float l_tot[4] = {0.f, 0.f, 0.f, 0.f};

    const u16* kbase  = kbuf  + (size_t)(b * G_KV + g) * S_LEN * HD;
    const u16* vtbase = vtbuf + (size_t)(b * G_KV + g) * HD * S_LEN;
    const u16* mbase  = mask_bf + ((size_t)b * S_LEN + s0) * S_LEN;

    int srow = tid >> 2, sc = (tid & 3) * 16;
    int prow = w * 16 + quad * 4;

    // prologue: prefetch tile 0 into registers
    uint4 kp0, kp1, vp0, vp1, mp0, mp1;
    {
        const u16* kr = kbase + (size_t)srow * HD + sc;
        kp0 = *(const uint4*)kr; kp1 = *(const uint4*)(kr + 8);
        const u16* vr = vtbase + (size_t)srow * S_LEN + sc;
        vp0 = *(const uint4*)vr; vp1 = *(const uint4*)(vr + 8);
        const u16* mr = mbase + (size_t)srow * S_LEN + sc;
        mp0 = *(const uint4*)mr; mp1 = *(const uint4*)(mr + 8);
    }

    for (int kt = 0; kt < 16; ++kt) {
        __syncthreads();   // previous iteration's LDS reads complete
        *(uint4*)&Ks[srow * 72 + sc]     = kp0;
        *(uint4*)&Ks[srow * 72 + sc + 8] = kp1;
        *(uint4*)&Vs[srow * 72 + sc]     = vp0;
        *(uint4*)&Vs[srow * 72 + sc + 8] = vp1;
        *(uint4*)&Ms[srow * 72 + sc]     = mp0;
        *(uint4*)&Ms[srow * 72 + sc + 8] = mp1;
        __syncthreads();   // staging visible

        // prefetch kt+1 (overlaps with compute below)
        if (kt < 15) {
            int nk = (kt + 1) * 64;
            const u16* kr = kbase + (size_t)(nk + srow) * HD + sc;
            kp0 = *(const uint4*)kr; kp1 = *(const uint4*)(kr + 8);
            const u16* vr = vtbase + (size_t)srow * S_LEN + nk + sc;
            vp0 = *(const uint4*)vr; vp1 = *(const uint4*)(vr + 8);
            const u16* mr = mbase + (size_t)srow * S_LEN + nk + sc;
            mp0 = *(const uint4*)mr; mp1 = *(const uint4*)(mr + 8);
        }

        // QK^T
        f32x4 p[4];
#pragma unroll
        for (int nt = 0; nt < 4; ++nt) {
            bf16x8 kf0 = *(const bf16x8*)&Ks[(nt * 16 + l16) * 72 + quad * 8];
            bf16x8 kf1 = *(const bf16x8*)&Ks[(nt * 16 + l16) * 72 + 32 + quad * 8];
            f32x4 z = (f32x4){0.f, 0.f, 0.f, 0.f};
            z = __builtin_amdgcn_mfma_f32_16x16x32_bf16(qf0, kf0, z, 0, 0, 0);
            p[nt] = __builtin_amdgcn_mfma_f32_16x16x32_bf16(qf1, kf1, z, 0, 0, 0);
        }

        // mask * exp, P strip, l partials
        float part[4] = {0.f, 0.f, 0.f, 0.f};
#pragma unroll
        for (int nt = 0; nt < 4; ++nt) {
#pragma unroll
            for (int reg = 0; reg < 4; ++reg) {
                int qr = prow + reg;
                float m = bf2f(Ms[qr * 72 + nt * 16 + l16]);
                float e = __expf(p[nt][reg] * m);
                part[reg] += e;
                Ps[qr * 72 + nt * 16 + l16] = f2bf(e);
            }
        }
        __syncthreads();   // P visible

#pragma unroll
        for (int reg = 0; reg < 4; ++reg) {
            float v = part[reg];
            v += __shfl_xor(v, 1);
            v += __shfl_xor(v, 2);
            v += __shfl_xor(v, 4);
            v += __shfl_xor(v, 8);
            l_tot[reg] += v;
        }

        bf16x8 pf0 = *(const bf16x8*)&Ps[(w * 16 + l16) * 72 + quad * 8];
        bf16x8 pf1 = *(const bf16x8*)&Ps[(w * 16 + l16) * 72 + 32 + quad * 8];
#pragma unroll
        for (int nt = 0; nt < 4; ++nt) {
            bf16x8 vf0 = *(const bf16x8*)&Vs[(nt * 16 + l16) * 72 + quad * 8];
            bf16x8 vf1 = *(const bf16x8*)&Vs[(nt * 16 + l16) * 72 + 32 + quad * 8];
            o_acc[nt] = __builtin_amdgcn_mfma_f32_16x16x32_bf16(pf0, vf0, o_acc[nt], 0, 0, 0);
            o_acc[nt] = __builtin_amdgcn_mfma_f32_16x16x32_bf16(pf1, vf1, o_acc[nt], 0, 0, 0);
        }
    }

#pragma unroll
    for (int reg = 0; reg < 4; ++reg) {
        int row = prow + reg;
        float inv = 1.0f / l_tot[reg];
        int sidx = s0 + row;
        u16* dst = aout + ((size_t)(b * S_LEN + sidx)) * HID + (g * R_REP + r) * HD;
#pragma unroll
        for (int nt = 0; nt < 4; ++nt)
            dst[nt * 16 + l16] = f2bf(o_acc[nt][reg] * inv);
    }
}

// ------- Output GEMM (m97-style): out = A(bf16) @ Wo + bo + x(fp32), fp32 out -------
__global__ __launch_bounds__(256) void gemm_o(const u16* __restrict__ A,
                                              const u16* __restrict__ WT,
                                              const float* __restrict__ bo,
                                              const float* __restrict__ Xres,
                                              float* __restrict__ out) {
    __shared__ __align__(16) u16 As[128 * 32];
    __shared__ __align__(16) u16 Bs[128 * 32];
    int tid = threadIdx.x;
    int w = tid >> 6, lane = tid & 63, quad = lane >> 4, l16 = lane & 15;
    int m0 = blockIdx.y * 128, n0 = blockIdx.x * 128;
    int wr = (w >> 1) * 64, wc = (w & 1) * 64;
    int srow = lane >> 2, scol = (lane & 3) * 8;

    f32x4 acc[4][4];
#pragma unroll
    for (int i = 0; i < 4; ++i)
#pragma unroll
        for (int j = 0; j < 4; ++j) acc[i][j] = (f32x4){0.f, 0.f, 0.f, 0.f};

    for (int k0 = 0; k0 < 2048; k0 += 32) {
#pragma unroll
        for (int c = 0; c < 2; ++c) {
            int row = c * 64 + w * 16 + srow;
            gload_lds16(&A[(size_t)(m0 + row) * 2048 + k0 + scol],  &As[(c * 64 + w * 16) * 32]);
            gload_lds16(&WT[(size_t)(n0 + row) * 2048 + k0 + scol], &Bs[(c * 64 + w * 16) * 32]);
        }
        __syncthreads();
        bf16x8 af[4], bfr[4];
#pragma unroll
        for (int mt = 0; mt < 4; ++mt)
            af[mt] = *(const bf16x8*)&As[(wr + mt * 16 + l16) * 32 + quad * 8];
#pragma unroll
        for (int nt = 0; nt < 4; ++nt)
            bfr[nt] = *(const bf16x8*)&Bs[(wc + nt * 16 + l16) * 32 + quad * 8];
#pragma unroll
        for (int mt = 0; mt < 4; ++mt)
#pragma unroll
            for (int nt = 0; nt < 4; ++nt)
                acc[mt][nt] = __builtin_amdgcn_mfma_f32_16x16x32_bf16(af[mt], bfr[nt], acc[mt][nt], 0, 0, 0);
        __syncthreads();
    }

#pragma unroll
    for (int nt = 0; nt < 4; ++nt) {
        int n = n0 + wc + nt * 16 + l16;
        float bias = bo[n];
#pragma unroll
        for (int mt = 0; mt < 4; ++mt) {
#pragma unroll
            for (int reg = 0; reg < 4; ++reg) {
                int m = m0 + wr + mt * 16 + quad * 4 + reg;
                out[(size_t)m * 2048 + n] = acc[mt][nt][reg] + bias + Xres[(size_t)m * 2048 + n];
            }
        }
    }
}

extern "C" void kernel_launch(void* const* d_in, const int* in_sizes, int n_in,
                              void* d_out, int out_size, void* d_ws, size_t ws_size,
                              hipStream_t stream) {
    const float* x    = (const float*)d_in[0];
    const float* mask = (const float*)d_in[1];
    const float* Wq   = (const float*)d_in[2];
    const float* bq   = (const float*)d_in[3];
    const float* Wk   = (const float*)d_in[4];
    const float* bk   = (const float*)d_in[5];
    const float* Wv   = (const float*)d_in[6];
    const float* bv   = (const float*)d_in[7];
    const float* Wo   = (const float*)d_in[8];
    const float* bo   = (const float*)d_in[9];
    float* out = (float*)d_out;

    u16* ws = (u16*)d_ws;
    size_t off = 0;
    u16* WqkvT = ws + off; off += (size_t)NQKV * 2048;
    u16* WoT   = ws + off; off += (size_t)2048 * 2048;
    u16* q_buf = ws + off; off += (size_t)BATCH * G_KV * R_REP * S_LEN * HD;
    u16* k_buf = ws + off; off += (size_t)BATCH * G_KV * S_LEN * HD;
    u16* v_buf = ws + off; off += (size_t)BATCH * G_KV * S_LEN * HD;  // transposed [b][g][d][s]
    u16* a_out = ws + off; off += (size_t)2048 * 2048;                // ~42 MB total
    u16* Xb      = a_out;   // alias: consumed by gemm_qkv before attn writes a_out
    u16* mask_bf = WqkvT;   // alias: WqkvT dead after gemm_qkv; mask_bf = 4 MB

    cvt_x<<<dim3(2048 * 2048 / (256 * 8)), 256, 0, stream>>>(x, Xb);

    dim3 tb(32, 8);
    transpose_cvt<<<dim3(64, 64), tb, 0, stream>>>(Wq, WqkvT, 2048, 2048);
    transpose_cvt<<<dim3(16, 64), tb, 0, stream>>>(Wk, WqkvT + (size_t)2048 * 2048, 2048, 512);
    transpose_cvt<<<dim3(16, 64), tb, 0, stream>>>(Wv, WqkvT + (size_t)2560 * 2048, 2048, 512);
    transpose_cvt<<<dim3(64, 64), tb, 0, stream>>>(Wo, WoT, 2048, 2048);

    gemm_qkv<<<dim3(NQKV / 128, 2048 / 128), 256, 0, stream>>>(Xb, WqkvT, bq, bk, bv,
                                                               q_buf, k_buf, v_buf);

    // mask fp32 -> bf16 (after gemm_qkv: reuses WqkvT space)
    cvt_x<<<dim3(BATCH * S_LEN * S_LEN / (256 * 8)), 256, 0, stream>>>(mask, mask_bf);

    attn_mfma<<<dim3(BATCH * G_KV * R_REP * (S_LEN / 64)), 256, 0, stream>>>(
        q_buf, k_buf, v_buf, mask_bf, a_out);

    gemm_o<<<dim3(2048 / 128, 2048 / 128), 256, 0, stream>>>(a_out, WoT, bo, x, out);
}

// Round 9
// 265.041 us; speedup vs baseline: 2.3312x; 1.0301x over previous
//
#include <hip/hip_runtime.h>

typedef unsigned short u16;
typedef unsigned int u32;
typedef __attribute__((ext_vector_type(8))) short bf16x8;
typedef __attribute__((ext_vector_type(4))) float f32x4;

#define HID 2048
#define S_LEN 1024
#define BATCH 2
#define G_KV 8
#define R_REP 4
#define HD 64
#define NQKV 3072  // 2048 q + 512 k + 512 v

__device__ __forceinline__ u16 f2bf(float f) {
    union { u32 u; float ff; } x; x.ff = f;
    u32 u = x.u;
    u += 0x7FFFu + ((u >> 16) & 1u);
    return (u16)(u >> 16);
}
__device__ __forceinline__ float bf2f(u16 v) {
    union { u32 u; float f; } x; x.u = ((u32)v) << 16; return x.f;
}

__device__ __forceinline__ void gload_lds16(const void* g, void* l) {
    __builtin_amdgcn_global_load_lds((const __attribute__((address_space(1))) void*)g,
                                     (__attribute__((address_space(3))) void*)l,
                                     16, 0, 0);
}

// ------- fp32 -> bf16 bulk convert (x) -------
__global__ __launch_bounds__(256) void cvt_x(const float* __restrict__ in,
                                             u16* __restrict__ out) {
    int i = (blockIdx.x * 256 + threadIdx.x) * 8;
    float4 a = *(const float4*)(in + i);
    float4 b = *(const float4*)(in + i + 4);
    u16 t[8] = {f2bf(a.x), f2bf(a.y), f2bf(a.z), f2bf(a.w),
                f2bf(b.x), f2bf(b.y), f2bf(b.z), f2bf(b.w)};
    *(uint4*)(out + i) = *(const uint4*)t;
}

// ------- mask permute: fp32 [B][S][S] -> bf16 fragment-order tiles -------
// out[((b*16+qblk)*16+kt)*4096 + tid*16 + nt*4 + reg] =
//   mask[b][qblk*64 + w*16+quad*4+reg][kt*64 + nt*16+l16],  tid=(w,quad,l16)
__global__ __launch_bounds__(256) void mask_perm(const float* __restrict__ mask,
                                                 u16* __restrict__ out) {
    __shared__ float tile[64 * 68];
    int bid = blockIdx.x;                 // 512 = B*16*16
    int kt = bid & 15, qblk = (bid >> 4) & 15, b = bid >> 8;
    int t = threadIdx.x;
    int row = t >> 2, c0 = (t & 3) * 16;
    const float* src = mask + ((size_t)b * S_LEN + qblk * 64 + row) * S_LEN + kt * 64 + c0;
#pragma unroll
    for (int i = 0; i < 4; ++i)
        *(float4*)&tile[row * 68 + c0 + i * 4] = *(const float4*)(src + i * 4);
    __syncthreads();
    int w = t >> 6, quad = (t >> 4) & 3, l16 = t & 15;
    int prow = w * 16 + quad * 4;
    u16 v[16];
#pragma unroll
    for (int nt = 0; nt < 4; ++nt)
#pragma unroll
        for (int reg = 0; reg < 4; ++reg)
            v[nt * 4 + reg] = f2bf(tile[(prow + reg) * 68 + nt * 16 + l16]);
    u16* dst = out + ((size_t)bid) * 4096 + t * 16;
    *(uint4*)dst = ((uint4*)v)[0];
    *(uint4*)(dst + 8) = ((uint4*)v)[1];
}

// ------- Transpose+convert: in fp32 [K][N] -> out bf16 [N][K] -------
__global__ __launch_bounds__(256) void transpose_cvt(const float* __restrict__ in,
                                                     u16* __restrict__ out,
                                                     int K, int N) {
    __shared__ float tile[32][33];
    int n0 = blockIdx.x * 32, k0 = blockIdx.y * 32;
    int tx = threadIdx.x, ty = threadIdx.y;
#pragma unroll
    for (int j = 0; j < 4; ++j)
        tile[ty + j * 8][tx] = in[(size_t)(k0 + ty + j * 8) * N + n0 + tx];
    __syncthreads();
#pragma unroll
    for (int j = 0; j < 4; ++j)
        out[(size_t)(n0 + ty + j * 8) * K + k0 + tx] = f2bf(tile[tx][ty + j * 8]);
}

// ------- QKV GEMM (m97-style): q pre-scaled by 0.125; V stored transposed -------
__global__ __launch_bounds__(256) void gemm_qkv(const u16* __restrict__ Xb,
                                                const u16* __restrict__ WT,
                                                const float* __restrict__ bq,
                                                const float* __restrict__ bk,
                                                const float* __restrict__ bv,
                                                u16* __restrict__ qb,
                                                u16* __restrict__ kb,
                                                u16* __restrict__ vb) {
    __shared__ __align__(16) u16 As[128 * 32];
    __shared__ __align__(16) u16 Bs[128 * 32];
    int tid = threadIdx.x;
    int w = tid >> 6, lane = tid & 63, quad = lane >> 4, l16 = lane & 15;
    int m0 = blockIdx.y * 128, n0 = blockIdx.x * 128;
    int wr = (w >> 1) * 64, wc = (w & 1) * 64;
    int srow = lane >> 2, scol = (lane & 3) * 8;

    f32x4 acc[4][4];
#pragma unroll
    for (int i = 0; i < 4; ++i)
#pragma unroll
        for (int j = 0; j < 4; ++j) acc[i][j] = (f32x4){0.f, 0.f, 0.f, 0.f};

    for (int k0 = 0; k0 < 2048; k0 += 32) {
#pragma unroll
        for (int c = 0; c < 2; ++c) {
            int row = c * 64 + w * 16 + srow;
            gload_lds16(&Xb[(size_t)(m0 + row) * 2048 + k0 + scol], &As[(c * 64 + w * 16) * 32]);
            gload_lds16(&WT[(size_t)(n0 + row) * 2048 + k0 + scol], &Bs[(c * 64 + w * 16) * 32]);
        }
        __syncthreads();
        bf16x8 af[4], bfr[4];
#pragma unroll
        for (int mt = 0; mt < 4; ++mt)
            af[mt] = *(const bf16x8*)&As[(wr + mt * 16 + l16) * 32 + quad * 8];
#pragma unroll
        for (int nt = 0; nt < 4; ++nt)
            bfr[nt] = *(const bf16x8*)&Bs[(wc + nt * 16 + l16) * 32 + quad * 8];
#pragma unroll
        for (int mt = 0; mt < 4; ++mt)
#pragma unroll
            for (int nt = 0; nt < 4; ++nt)
                acc[mt][nt] = __builtin_amdgcn_mfma_f32_16x16x32_bf16(af[mt], bfr[nt], acc[mt][nt], 0, 0, 0);
        __syncthreads();
    }

#pragma unroll
    for (int nt = 0; nt < 4; ++nt) {
        int n = n0 + wc + nt * 16 + l16;
        float bias;
        if (n < 2048) bias = bq[n];
        else if (n < 2560) bias = bk[n - 2048];
        else bias = bv[n - 2560];
#pragma unroll
        for (int mt = 0; mt < 4; ++mt) {
#pragma unroll
            for (int reg = 0; reg < 4; ++reg) {
                int m = m0 + wr + mt * 16 + quad * 4 + reg;
                float val = acc[mt][nt][reg] + bias;
                int b = m >> 10, s = m & 1023;
                if (n < 2048) {
                    int g = n >> 8, r = (n >> 6) & 3, d = n & 63;
                    qb[((((size_t)(b * G_KV + g) * R_REP + r) * S_LEN) + s) * HD + d] = f2bf(val * 0.125f);
                } else if (n < 2560) {
                    int n2 = n - 2048, g = n2 >> 6, d = n2 & 63;
                    kb[(((size_t)(b * G_KV + g) * S_LEN) + s) * HD + d] = f2bf(val);
                } else {
                    int n2 = n - 2560, g = n2 >> 6, d = n2 & 63;
                    vb[(((size_t)(b * G_KV + g) * HD + d) * S_LEN) + s] = f2bf(val);  // V^T
                }
            }
        }
    }
}

// ------- Attention: MFMA flash; mask from permuted global (registers, no LDS) -------
__global__ __launch_bounds__(256) void attn_mfma(const u16* __restrict__ qbuf,
                                                 const u16* __restrict__ kbuf,
                                                 const u16* __restrict__ vtbuf,
                                                 const u16* __restrict__ mask_pm,
                                                 u16* __restrict__ aout) {
    __shared__ __align__(16) u16 Ks[64 * 72];   // [key][dim]
    __shared__ __align__(16) u16 Vs[64 * 72];   // [dim][key]
    __shared__ __align__(16) u16 Ps[64 * 72];   // [q][key] bf16

    int d = blockIdx.x;
    int xcd = d & 7, j = d >> 3;
    int pr = xcd * 2 + (j >> 6);          // (b,g) pair 0..15
    int r = (j >> 4) & 3, qblk = j & 15;
    int b = pr >> 3, g = pr & 7;

    int tid = threadIdx.x;
    int w = tid >> 6, lane = tid & 63, quad = lane >> 4, l16 = lane & 15;
    int s0 = qblk * 64;

    const u16* qrow = qbuf +
        ((((size_t)(b * G_KV + g) * R_REP + r) * S_LEN) + s0 + w * 16 + l16) * HD;
    bf16x8 qf0 = *(const bf16x8*)(qrow + quad * 8);
    bf16x8 qf1 = *(const bf16x8*)(qrow + 32 + quad * 8);

    f32x4 o_acc[4];
#pragma unroll
    for (int i = 0; i < 4; ++i) o_acc[i] = (f32x4){0.f, 0.f, 0.f, 0.f};
    float l_tot[4] = {0.f, 0.f, 0.f, 0.f};

    const u16* kbase  = kbuf  + (size_t)(b * G_KV + g) * S_LEN * HD;
    const u16* vtbase = vtbuf + (size_t)(b * G_KV + g) * HD * S_LEN;
    const u16* mbase  = mask_pm + ((size_t)(b * 16 + qblk) * 16) * 4096 + tid * 16;

    int srow = tid >> 2, sc = (tid & 3) * 16;
    int prow = w * 16 + quad * 4;

    // prologue: prefetch tile 0
    uint4 kp0, kp1, vp0, vp1, mp0, mp1;
    {
        const u16* kr = kbase + (size_t)srow * HD + sc;
        kp0 = *(const uint4*)kr; kp1 = *(const uint4*)(kr + 8);
        const u16* vr = vtbase + (size_t)srow * S_LEN + sc;
        vp0 = *(const uint4*)vr; vp1 = *(const uint4*)(vr + 8);
        mp0 = *(const uint4*)mbase; mp1 = *(const uint4*)(mbase + 8);
    }

    for (int kt = 0; kt < 16; ++kt) {
        __syncthreads();   // previous iteration's LDS reads complete
        *(uint4*)&Ks[srow * 72 + sc]     = kp0;
        *(uint4*)&Ks[srow * 72 + sc + 8] = kp1;
        *(uint4*)&Vs[srow * 72 + sc]     = vp0;
        *(uint4*)&Vs[srow * 72 + sc + 8] = vp1;
        uint4 m0c = mp0, m1c = mp1;       // current mask values (registers)
        __syncthreads();   // staging visible

        // prefetch kt+1 (overlaps compute)
        if (kt < 15) {
            int nk = (kt + 1) * 64;
            const u16* kr = kbase + (size_t)(nk + srow) * HD + sc;
            kp0 = *(const uint4*)kr; kp1 = *(const uint4*)(kr + 8);
            const u16* vr = vtbase + (size_t)srow * S_LEN + nk + sc;
            vp0 = *(const uint4*)vr; vp1 = *(const uint4*)(vr + 8);
            const u16* mr = mbase + (size_t)(kt + 1) * 4096;
            mp0 = *(const uint4*)mr; mp1 = *(const uint4*)(mr + 8);
        }

        // QK^T
        f32x4 p[4];
#pragma unroll
        for (int nt = 0; nt < 4; ++nt) {
            bf16x8 kf0 = *(const bf16x8*)&Ks[(nt * 16 + l16) * 72 + quad * 8];
            bf16x8 kf1 = *(const bf16x8*)&Ks[(nt * 16 + l16) * 72 + 32 + quad * 8];
            f32x4 z = (f32x4){0.f, 0.f, 0.f, 0.f};
            z = __builtin_amdgcn_mfma_f32_16x16x32_bf16(qf0, kf0, z, 0, 0, 0);
            p[nt] = __builtin_amdgcn_mfma_f32_16x16x32_bf16(qf1, kf1, z, 0, 0, 0);
        }

        // mask * exp, P strip, l partials
        const u16* mv0 = (const u16*)&m0c;
        const u16* mv1 = (const u16*)&m1c;
        float part[4] = {0.f, 0.f, 0.f, 0.f};
#pragma unroll
        for (int nt = 0; nt < 4; ++nt) {
#pragma unroll
            for (int reg = 0; reg < 4; ++reg) {
                int idx = nt * 4 + reg;
                float m = bf2f(idx < 8 ? mv0[idx] : mv1[idx - 8]);
                float e = __expf(p[nt][reg] * m);
                part[reg] += e;
                Ps[(prow + reg) * 72 + nt * 16 + l16] = f2bf(e);
            }
        }
        __syncthreads();   // P visible

#pragma unroll
        for (int reg = 0; reg < 4; ++reg) {
            float v = part[reg];
            v += __shfl_xor(v, 1);
            v += __shfl_xor(v, 2);
            v += __shfl_xor(v, 4);
            v += __shfl_xor(v, 8);
            l_tot[reg] += v;
        }

        bf16x8 pf0 = *(const bf16x8*)&Ps[(w * 16 + l16) * 72 + quad * 8];
        bf16x8 pf1 = *(const bf16x8*)&Ps[(w * 16 + l16) * 72 + 32 + quad * 8];
#pragma unroll
        for (int nt = 0; nt < 4; ++nt) {
            bf16x8 vf0 = *(const bf16x8*)&Vs[(nt * 16 + l16) * 72 + quad * 8];
            bf16x8 vf1 = *(const bf16x8*)&Vs[(nt * 16 + l16) * 72 + 32 + quad * 8];
            o_acc[nt] = __builtin_amdgcn_mfma_f32_16x16x32_bf16(pf0, vf0, o_acc[nt], 0, 0, 0);
            o_acc[nt] = __builtin_amdgcn_mfma_f32_16x16x32_bf16(pf1, vf1, o_acc[nt], 0, 0, 0);
        }
    }

#pragma unroll
    for (int reg = 0; reg < 4; ++reg) {
        int row = prow + reg;
        float inv = 1.0f / l_tot[reg];
        int sidx = s0 + row;
        u16* dst = aout + ((size_t)(b * S_LEN + sidx)) * HID + (g * R_REP + r) * HD;
#pragma unroll
        for (int nt = 0; nt < 4; ++nt)
            dst[nt * 16 + l16] = f2bf(o_acc[nt][reg] * inv);
    }
}

// ------- Output GEMM (m97-style): out = A(bf16) @ Wo + bo + x(fp32), fp32 out -------
__global__ __launch_bounds__(256) void gemm_o(const u16* __restrict__ A,
                                              const u16* __restrict__ WT,
                                              const float* __restrict__ bo,
                                              const float* __restrict__ Xres,
                                              float* __restrict__ out) {
    __shared__ __align__(16) u16 As[128 * 32];
    __shared__ __align__(16) u16 Bs[128 * 32];
    int tid = threadIdx.x;
    int w = tid >> 6, lane = tid & 63, quad = lane >> 4, l16 = lane & 15;
    int m0 = blockIdx.y * 128, n0 = blockIdx.x * 128;
    int wr = (w >> 1) * 64, wc = (w & 1) * 64;
    int srow = lane >> 2, scol = (lane & 3) * 8;

    f32x4 acc[4][4];
#pragma unroll
    for (int i = 0; i < 4; ++i)
#pragma unroll
        for (int j = 0; j < 4; ++j) acc[i][j] = (f32x4){0.f, 0.f, 0.f, 0.f};

    for (int k0 = 0; k0 < 2048; k0 += 32) {
#pragma unroll
        for (int c = 0; c < 2; ++c) {
            int row = c * 64 + w * 16 + srow;
            gload_lds16(&A[(size_t)(m0 + row) * 2048 + k0 + scol],  &As[(c * 64 + w * 16) * 32]);
            gload_lds16(&WT[(size_t)(n0 + row) * 2048 + k0 + scol], &Bs[(c * 64 + w * 16) * 32]);
        }
        __syncthreads();
        bf16x8 af[4], bfr[4];
#pragma unroll
        for (int mt = 0; mt < 4; ++mt)
            af[mt] = *(const bf16x8*)&As[(wr + mt * 16 + l16) * 32 + quad * 8];
#pragma unroll
        for (int nt = 0; nt < 4; ++nt)
            bfr[nt] = *(const bf16x8*)&Bs[(wc + nt * 16 + l16) * 32 + quad * 8];
#pragma unroll
        for (int mt = 0; mt < 4; ++mt)
#pragma unroll
            for (int nt = 0; nt < 4; ++nt)
                acc[mt][nt] = __builtin_amdgcn_mfma_f32_16x16x32_bf16(af[mt], bfr[nt], acc[mt][nt], 0, 0, 0);
        __syncthreads();
    }

#pragma unroll
    for (int nt = 0; nt < 4; ++nt) {
        int n = n0 + wc + nt * 16 + l16;
        float bias = bo[n];
#pragma unroll
        for (int mt = 0; mt < 4; ++mt) {
#pragma unroll
            for (int reg = 0; reg < 4; ++reg) {
                int m = m0 + wr + mt * 16 + quad * 4 + reg;
                out[(size_t)m * 2048 + n] = acc[mt][nt][reg] + bias + Xres[(size_t)m * 2048 + n];
            }
        }
    }
}

extern "C" void kernel_launch(void* const* d_in, const int* in_sizes, int n_in,
                              void* d_out, int out_size, void* d_ws, size_t ws_size,
                              hipStream_t stream) {
    const float* x    = (const float*)d_in[0];
    const float* mask = (const float*)d_in[1];
    const float* Wq   = (const float*)d_in[2];
    const float* bq   = (const float*)d_in[3];
    const float* Wk   = (const float*)d_in[4];
    const float* bk   = (const float*)d_in[5];
    const float* Wv   = (const float*)d_in[6];
    const float* bv   = (const float*)d_in[7];
    const float* Wo   = (const float*)d_in[8];
    const float* bo   = (const float*)d_in[9];
    float* out = (float*)d_out;

    u16* ws = (u16*)d_ws;
    size_t off = 0;
    u16* WqkvT = ws + off; off += (size_t)NQKV * 2048;
    u16* WoT   = ws + off; off += (size_t)2048 * 2048;
    u16* q_buf = ws + off; off += (size_t)BATCH * G_KV * R_REP * S_LEN * HD;
    u16* k_buf = ws + off; off += (size_t)BATCH * G_KV * S_LEN * HD;
    u16* v_buf = ws + off; off += (size_t)BATCH * G_KV * S_LEN * HD;  // transposed [b][g][d][s]
    u16* a_out = ws + off; off += (size_t)2048 * 2048;                // ~42 MB total
    u16* Xb      = a_out;   // alias: consumed by gemm_qkv before attn writes a_out
    u16* mask_pm = WqkvT;   // alias: WqkvT dead after gemm_qkv; 4 MB needed

    cvt_x<<<dim3(2048 * 2048 / (256 * 8)), 256, 0, stream>>>(x, Xb);

    dim3 tb(32, 8);
    transpose_cvt<<<dim3(64, 64), tb, 0, stream>>>(Wq, WqkvT, 2048, 2048);
    transpose_cvt<<<dim3(16, 64), tb, 0, stream>>>(Wk, WqkvT + (size_t)2048 * 2048, 2048, 512);
    transpose_cvt<<<dim3(16, 64), tb, 0, stream>>>(Wv, WqkvT + (size_t)2560 * 2048, 2048, 512);
    transpose_cvt<<<dim3(64, 64), tb, 0, stream>>>(Wo, WoT, 2048, 2048);

    gemm_qkv<<<dim3(NQKV / 128, 2048 / 128), 256, 0, stream>>>(Xb, WqkvT, bq, bk, bv,
                                                               q_buf, k_buf, v_buf);

    // mask fp32 -> permuted bf16 tiles (after gemm_qkv: reuses WqkvT space)
    mask_perm<<<dim3(BATCH * 16 * 16), 256, 0, stream>>>(mask, mask_pm);

    attn_mfma<<<dim3(BATCH * G_KV * R_REP * (S_LEN / 64)), 256, 0, stream>>>(
        q_buf, k_buf, v_buf, mask_pm, a_out);

    gemm_o<<<dim3(2048 / 128, 2048 / 128), 256, 0, stream>>>(a_out, WoT, bo, x, out);
}

// Round 10
// 249.410 us; speedup vs baseline: 2.4773x; 1.0627x over previous
//
#include <hip/hip_runtime.h>

typedef unsigned short u16;
typedef unsigned int u32;
typedef __attribute__((ext_vector_type(8))) short bf16x8;
typedef __attribute__((ext_vector_type(4))) float f32x4;

#define HID 2048
#define S_LEN 1024
#define BATCH 2
#define G_KV 8
#define R_REP 4
#define HD 64
#define NQKV 3072  // 2048 q + 512 k + 512 v

__device__ __forceinline__ u16 f2bf(float f) {
    union { u32 u; float ff; } x; x.ff = f;
    u32 u = x.u;
    u += 0x7FFFu + ((u >> 16) & 1u);
    return (u16)(u >> 16);
}
__device__ __forceinline__ float bf2f(u16 v) {
    union { u32 u; float f; } x; x.u = ((u32)v) << 16; return x.f;
}

__device__ __forceinline__ void gload_lds16(const void* g, void* l) {
    __builtin_amdgcn_global_load_lds((const __attribute__((address_space(1))) void*)g,
                                     (__attribute__((address_space(3))) void*)l,
                                     16, 0, 0);
}

// ------- fp32 -> bf16 bulk convert (x) -------
__global__ __launch_bounds__(256) void cvt_x(const float* __restrict__ in,
                                             u16* __restrict__ out) {
    int i = (blockIdx.x * 256 + threadIdx.x) * 8;
    float4 a = *(const float4*)(in + i);
    float4 b = *(const float4*)(in + i + 4);
    u16 t[8] = {f2bf(a.x), f2bf(a.y), f2bf(a.z), f2bf(a.w),
                f2bf(b.x), f2bf(b.y), f2bf(b.z), f2bf(b.w)};
    *(uint4*)(out + i) = *(const uint4*)t;
}

// ------- mask permute: fp32 [B][S][S] -> bf16 fragment-order tiles -------
__global__ __launch_bounds__(256) void mask_perm(const float* __restrict__ mask,
                                                 u16* __restrict__ out) {
    __shared__ float tile[64 * 68];
    int bid = blockIdx.x;                 // 512 = B*16*16
    int kt = bid & 15, qblk = (bid >> 4) & 15, b = bid >> 8;
    int t = threadIdx.x;
    int row = t >> 2, c0 = (t & 3) * 16;
    const float* src = mask + ((size_t)b * S_LEN + qblk * 64 + row) * S_LEN + kt * 64 + c0;
#pragma unroll
    for (int i = 0; i < 4; ++i)
        *(float4*)&tile[row * 68 + c0 + i * 4] = *(const float4*)(src + i * 4);
    __syncthreads();
    int w = t >> 6, quad = (t >> 4) & 3, l16 = t & 15;
    int prow = w * 16 + quad * 4;
    u16 v[16];
#pragma unroll
    for (int nt = 0; nt < 4; ++nt)
#pragma unroll
        for (int reg = 0; reg < 4; ++reg)
            v[nt * 4 + reg] = f2bf(tile[(prow + reg) * 68 + nt * 16 + l16]);
    u16* dst = out + ((size_t)bid) * 4096 + t * 16;
    *(uint4*)dst = ((uint4*)v)[0];
    *(uint4*)(dst + 8) = ((uint4*)v)[1];
}

// ------- Fused W transpose+convert: {Wq|Wk|Wv} fp32 [2048][*] -> WqkvT bf16 [3072][2048] -------
__global__ __launch_bounds__(256) void transpose_qkv(const float* __restrict__ Wq,
                                                     const float* __restrict__ Wk,
                                                     const float* __restrict__ Wv,
                                                     u16* __restrict__ out) {
    __shared__ float tile[32][33];
    int n0 = blockIdx.x * 32, k0 = blockIdx.y * 32;
    const float* in; int N, nc0;
    if (n0 < 2048)      { in = Wq; N = 2048; nc0 = n0; }
    else if (n0 < 2560) { in = Wk; N = 512;  nc0 = n0 - 2048; }
    else                { in = Wv; N = 512;  nc0 = n0 - 2560; }
    int tx = threadIdx.x, ty = threadIdx.y;
#pragma unroll
    for (int j = 0; j < 4; ++j)
        tile[ty + j * 8][tx] = in[(size_t)(k0 + ty + j * 8) * N + nc0 + tx];
    __syncthreads();
#pragma unroll
    for (int j = 0; j < 4; ++j)
        out[(size_t)(n0 + ty + j * 8) * 2048 + k0 + tx] = f2bf(tile[tx][ty + j * 8]);
}

// ------- Transpose+convert: in fp32 [K][N] -> out bf16 [N][K] -------
__global__ __launch_bounds__(256) void transpose_cvt(const float* __restrict__ in,
                                                     u16* __restrict__ out,
                                                     int K, int N) {
    __shared__ float tile[32][33];
    int n0 = blockIdx.x * 32, k0 = blockIdx.y * 32;
    int tx = threadIdx.x, ty = threadIdx.y;
#pragma unroll
    for (int j = 0; j < 4; ++j)
        tile[ty + j * 8][tx] = in[(size_t)(k0 + ty + j * 8) * N + n0 + tx];
    __syncthreads();
#pragma unroll
    for (int j = 0; j < 4; ++j)
        out[(size_t)(n0 + ty + j * 8) * K + k0 + tx] = f2bf(tile[tx][ty + j * 8]);
}

// ------- QKV GEMM: BM=64 BN=128 BK=32, 768 blocks (3/CU); q pre-scaled; V^T -------
__global__ __launch_bounds__(256) void gemm_qkv(const u16* __restrict__ Xb,
                                                const u16* __restrict__ WT,
                                                const float* __restrict__ bq,
                                                const float* __restrict__ bk,
                                                const float* __restrict__ bv,
                                                u16* __restrict__ qb,
                                                u16* __restrict__ kb,
                                                u16* __restrict__ vb) {
    __shared__ __align__(16) u16 As[64 * 32];
    __shared__ __align__(16) u16 Bs[128 * 32];
    int tid = threadIdx.x;
    int w = tid >> 6, lane = tid & 63, quad = lane >> 4, l16 = lane & 15;
    int m0 = blockIdx.y * 64, n0 = blockIdx.x * 128;
    int wr = (w >> 1) * 32, wc = (w & 1) * 64;   // wave tile 32x64
    int srow = lane >> 2, scol = (lane & 3) * 8;

    f32x4 acc[2][4];
#pragma unroll
    for (int i = 0; i < 2; ++i)
#pragma unroll
        for (int j = 0; j < 4; ++j) acc[i][j] = (f32x4){0.f, 0.f, 0.f, 0.f};

    for (int k0 = 0; k0 < 2048; k0 += 32) {
        // A: 64 rows = 4 strips, one per wave
        gload_lds16(&Xb[(size_t)(m0 + w * 16 + srow) * 2048 + k0 + scol], &As[(w * 16) * 32]);
        // B: 128 rows = 8 strips, two per wave
#pragma unroll
        for (int c = 0; c < 2; ++c) {
            int row = w * 32 + c * 16;
            gload_lds16(&WT[(size_t)(n0 + row + srow) * 2048 + k0 + scol], &Bs[row * 32]);
        }
        __syncthreads();
        bf16x8 af[2], bfr[4];
#pragma unroll
        for (int mt = 0; mt < 2; ++mt)
            af[mt] = *(const bf16x8*)&As[(wr + mt * 16 + l16) * 32 + quad * 8];
#pragma unroll
        for (int nt = 0; nt < 4; ++nt)
            bfr[nt] = *(const bf16x8*)&Bs[(wc + nt * 16 + l16) * 32 + quad * 8];
#pragma unroll
        for (int mt = 0; mt < 2; ++mt)
#pragma unroll
            for (int nt = 0; nt < 4; ++nt)
                acc[mt][nt] = __builtin_amdgcn_mfma_f32_16x16x32_bf16(af[mt], bfr[nt], acc[mt][nt], 0, 0, 0);
        __syncthreads();
    }

#pragma unroll
    for (int nt = 0; nt < 4; ++nt) {
        int n = n0 + wc + nt * 16 + l16;
        float bias;
        if (n < 2048) bias = bq[n];
        else if (n < 2560) bias = bk[n - 2048];
        else bias = bv[n - 2560];
#pragma unroll
        for (int mt = 0; mt < 2; ++mt) {
#pragma unroll
            for (int reg = 0; reg < 4; ++reg) {
                int m = m0 + wr + mt * 16 + quad * 4 + reg;
                float val = acc[mt][nt][reg] + bias;
                int b = m >> 10, s = m & 1023;
                if (n < 2048) {
                    int g = n >> 8, r = (n >> 6) & 3, d = n & 63;
                    qb[((((size_t)(b * G_KV + g) * R_REP + r) * S_LEN) + s) * HD + d] = f2bf(val * 0.125f);
                } else if (n < 2560) {
                    int n2 = n - 2048, g = n2 >> 6, d = n2 & 63;
                    kb[(((size_t)(b * G_KV + g) * S_LEN) + s) * HD + d] = f2bf(val);
                } else {
                    int n2 = n - 2560, g = n2 >> 6, d = n2 & 63;
                    vb[(((size_t)(b * G_KV + g) * HD + d) * S_LEN) + s] = f2bf(val);  // V^T
                }
            }
        }
    }
}

// ------- Attention: MFMA flash; mask from permuted global (registers, no LDS) -------
__global__ __launch_bounds__(256) void attn_mfma(const u16* __restrict__ qbuf,
                                                 const u16* __restrict__ kbuf,
                                                 const u16* __restrict__ vtbuf,
                                                 const u16* __restrict__ mask_pm,
                                                 u16* __restrict__ aout) {
    __shared__ __align__(16) u16 Ks[64 * 72];   // [key][dim]
    __shared__ __align__(16) u16 Vs[64 * 72];   // [dim][key]
    __shared__ __align__(16) u16 Ps[64 * 72];   // [q][key] bf16

    int d = blockIdx.x;
    int xcd = d & 7, j = d >> 3;
    int pr = xcd * 2 + (j >> 6);          // (b,g) pair 0..15
    int r = (j >> 4) & 3, qblk = j & 15;
    int b = pr >> 3, g = pr & 7;

    int tid = threadIdx.x;
    int w = tid >> 6, lane = tid & 63, quad = lane >> 4, l16 = lane & 15;
    int s0 = qblk * 64;

    const u16* qrow = qbuf +
        ((((size_t)(b * G_KV + g) * R_REP + r) * S_LEN) + s0 + w * 16 + l16) * HD;
    bf16x8 qf0 = *(const bf16x8*)(qrow + quad * 8);
    bf16x8 qf1 = *(const bf16x8*)(qrow + 32 + quad * 8);

    f32x4 o_acc[4];
#pragma unroll
    for (int i = 0; i < 4; ++i) o_acc[i] = (f32x4){0.f, 0.f, 0.f, 0.f};
    float l_tot[4] = {0.f, 0.f, 0.f, 0.f};

    const u16* kbase  = kbuf  + (size_t)(b * G_KV + g) * S_LEN * HD;
    const u16* vtbase = vtbuf + (size_t)(b * G_KV + g) * HD * S_LEN;
    const u16* mbase  = mask_pm + ((size_t)(b * 16 + qblk) * 16) * 4096 + tid * 16;

    int srow = tid >> 2, sc = (tid & 3) * 16;
    int prow = w * 16 + quad * 4;

    uint4 kp0, kp1, vp0, vp1, mp0, mp1;
    {
        const u16* kr = kbase + (size_t)srow * HD + sc;
        kp0 = *(const uint4*)kr; kp1 = *(const uint4*)(kr + 8);
        const u16* vr = vtbase + (size_t)srow * S_LEN + sc;
        vp0 = *(const uint4*)vr; vp1 = *(const uint4*)(vr + 8);
        mp0 = *(const uint4*)mbase; mp1 = *(const uint4*)(mbase + 8);
    }

    for (int kt = 0; kt < 16; ++kt) {
        __syncthreads();
        *(uint4*)&Ks[srow * 72 + sc]     = kp0;
        *(uint4*)&Ks[srow * 72 + sc + 8] = kp1;
        *(uint4*)&Vs[srow * 72 + sc]     = vp0;
        *(uint4*)&Vs[srow * 72 + sc + 8] = vp1;
        uint4 m0c = mp0, m1c = mp1;
        __syncthreads();

        if (kt < 15) {
            int nk = (kt + 1) * 64;
            const u16* kr = kbase + (size_t)(nk + srow) * HD + sc;
            kp0 = *(const uint4*)kr; kp1 = *(const uint4*)(kr + 8);
            const u16* vr = vtbase + (size_t)srow * S_LEN + nk + sc;
            vp0 = *(const uint4*)vr; vp1 = *(const uint4*)(vr + 8);
            const u16* mr = mbase + (size_t)(kt + 1) * 4096;
            mp0 = *(const uint4*)mr; mp1 = *(const uint4*)(mr + 8);
        }

        f32x4 p[4];
#pragma unroll
        for (int nt = 0; nt < 4; ++nt) {
            bf16x8 kf0 = *(const bf16x8*)&Ks[(nt * 16 + l16) * 72 + quad * 8];
            bf16x8 kf1 = *(const bf16x8*)&Ks[(nt * 16 + l16) * 72 + 32 + quad * 8];
            f32x4 z = (f32x4){0.f, 0.f, 0.f, 0.f};
            z = __builtin_amdgcn_mfma_f32_16x16x32_bf16(qf0, kf0, z, 0, 0, 0);
            p[nt] = __builtin_amdgcn_mfma_f32_16x16x32_bf16(qf1, kf1, z, 0, 0, 0);
        }

        const u16* mv0 = (const u16*)&m0c;
        const u16* mv1 = (const u16*)&m1c;
        float part[4] = {0.f, 0.f, 0.f, 0.f};
#pragma unroll
        for (int nt = 0; nt < 4; ++nt) {
#pragma unroll
            for (int reg = 0; reg < 4; ++reg) {
                int idx = nt * 4 + reg;
                float m = bf2f(idx < 8 ? mv0[idx] : mv1[idx - 8]);
                float e = __expf(p[nt][reg] * m);
                part[reg] += e;
                Ps[(prow + reg) * 72 + nt * 16 + l16] = f2bf(e);
            }
        }
        __syncthreads();

#pragma unroll
        for (int reg = 0; reg < 4; ++reg) {
            float v = part[reg];
            v += __shfl_xor(v, 1);
            v += __shfl_xor(v, 2);
            v += __shfl_xor(v, 4);
            v += __shfl_xor(v, 8);
            l_tot[reg] += v;
        }

        bf16x8 pf0 = *(const bf16x8*)&Ps[(w * 16 + l16) * 72 + quad * 8];
        bf16x8 pf1 = *(const bf16x8*)&Ps[(w * 16 + l16) * 72 + 32 + quad * 8];
#pragma unroll
        for (int nt = 0; nt < 4; ++nt) {
            bf16x8 vf0 = *(const bf16x8*)&Vs[(nt * 16 + l16) * 72 + quad * 8];
            bf16x8 vf1 = *(const bf16x8*)&Vs[(nt * 16 + l16) * 72 + 32 + quad * 8];
            o_acc[nt] = __builtin_amdgcn_mfma_f32_16x16x32_bf16(pf0, vf0, o_acc[nt], 0, 0, 0);
            o_acc[nt] = __builtin_amdgcn_mfma_f32_16x16x32_bf16(pf1, vf1, o_acc[nt], 0, 0, 0);
        }
    }

#pragma unroll
    for (int reg = 0; reg < 4; ++reg) {
        int row = prow + reg;
        float inv = 1.0f / l_tot[reg];
        int sidx = s0 + row;
        u16* dst = aout + ((size_t)(b * S_LEN + sidx)) * HID + (g * R_REP + r) * HD;
#pragma unroll
        for (int nt = 0; nt < 4; ++nt)
            dst[nt * 16 + l16] = f2bf(o_acc[nt][reg] * inv);
    }
}

// ------- Output GEMM: BM=64 BN=128, 512 blocks (2/CU); fp32 out + bias + residual -------
__global__ __launch_bounds__(256) void gemm_o(const u16* __restrict__ A,
                                              const u16* __restrict__ WT,
                                              const float* __restrict__ bo,
                                              const float* __restrict__ Xres,
                                              float* __restrict__ out) {
    __shared__ __align__(16) u16 As[64 * 32];
    __shared__ __align__(16) u16 Bs[128 * 32];
    int tid = threadIdx.x;
    int w = tid >> 6, lane = tid & 63, quad = lane >> 4, l16 = lane & 15;
    int m0 = blockIdx.y * 64, n0 = blockIdx.x * 128;
    int wr = (w >> 1) * 32, wc = (w & 1) * 64;
    int srow = lane >> 2, scol = (lane & 3) * 8;

    f32x4 acc[2][4];
#pragma unroll
    for (int i = 0; i < 2; ++i)
#pragma unroll
        for (int j = 0; j < 4; ++j) acc[i][j] = (f32x4){0.f, 0.f, 0.f, 0.f};

    for (int k0 = 0; k0 < 2048; k0 += 32) {
        gload_lds16(&A[(size_t)(m0 + w * 16 + srow) * 2048 + k0 + scol], &As[(w * 16) * 32]);
#pragma unroll
        for (int c = 0; c < 2; ++c) {
            int row = w * 32 + c * 16;
            gload_lds16(&WT[(size_t)(n0 + row + srow) * 2048 + k0 + scol], &Bs[row * 32]);
        }
        __syncthreads();
        bf16x8 af[2], bfr[4];
#pragma unroll
        for (int mt = 0; mt < 2; ++mt)
            af[mt] = *(const bf16x8*)&As[(wr + mt * 16 + l16) * 32 + quad * 8];
#pragma unroll
        for (int nt = 0; nt < 4; ++nt)
            bfr[nt] = *(const bf16x8*)&Bs[(wc + nt * 16 + l16) * 32 + quad * 8];
#pragma unroll
        for (int mt = 0; mt < 2; ++mt)
#pragma unroll
            for (int nt = 0; nt < 4; ++nt)
                acc[mt][nt] = __builtin_amdgcn_mfma_f32_16x16x32_bf16(af[mt], bfr[nt], acc[mt][nt], 0, 0, 0);
        __syncthreads();
    }

#pragma unroll
    for (int nt = 0; nt < 4; ++nt) {
        int n = n0 + wc + nt * 16 + l16;
        float bias = bo[n];
#pragma unroll
        for (int mt = 0; mt < 2; ++mt) {
#pragma unroll
            for (int reg = 0; reg < 4; ++reg) {
                int m = m0 + wr + mt * 16 + quad * 4 + reg;
                out[(size_t)m * 2048 + n] = acc[mt][nt][reg] + bias + Xres[(size_t)m * 2048 + n];
            }
        }
    }
}

extern "C" void kernel_launch(void* const* d_in, const int* in_sizes, int n_in,
                              void* d_out, int out_size, void* d_ws, size_t ws_size,
                              hipStream_t stream) {
    const float* x    = (const float*)d_in[0];
    const float* mask = (const float*)d_in[1];
    const float* Wq   = (const float*)d_in[2];
    const float* bq   = (const float*)d_in[3];
    const float* Wk   = (const float*)d_in[4];
    const float* bk   = (const float*)d_in[5];
    const float* Wv   = (const float*)d_in[6];
    const float* bv   = (const float*)d_in[7];
    const float* Wo   = (const float*)d_in[8];
    const float* bo   = (const float*)d_in[9];
    float* out = (float*)d_out;

    u16* ws = (u16*)d_ws;
    size_t off = 0;
    u16* WqkvT = ws + off; off += (size_t)NQKV * 2048;
    u16* WoT   = ws + off; off += (size_t)2048 * 2048;
    u16* q_buf = ws + off; off += (size_t)BATCH * G_KV * R_REP * S_LEN * HD;
    u16* k_buf = ws + off; off += (size_t)BATCH * G_KV * S_LEN * HD;
    u16* v_buf = ws + off; off += (size_t)BATCH * G_KV * S_LEN * HD;  // transposed [b][g][d][s]
    u16* a_out = ws + off; off += (size_t)2048 * 2048;
    u16* Xb      = a_out;   // alias: consumed by gemm_qkv before attn writes a_out
    u16* mask_pm = WqkvT;   // alias: WqkvT dead after gemm_qkv; 4 MB needed

    cvt_x<<<dim3(2048 * 2048 / (256 * 8)), 256, 0, stream>>>(x, Xb);

    dim3 tb(32, 8);
    transpose_qkv<<<dim3(96, 64), tb, 0, stream>>>(Wq, Wk, Wv, WqkvT);
    transpose_cvt<<<dim3(64, 64), tb, 0, stream>>>(Wo, WoT, 2048, 2048);

    gemm_qkv<<<dim3(NQKV / 128, 2048 / 64), 256, 0, stream>>>(Xb, WqkvT, bq, bk, bv,
                                                              q_buf, k_buf, v_buf);

    mask_perm<<<dim3(BATCH * 16 * 16), 256, 0, stream>>>(mask, mask_pm);

    attn_mfma<<<dim3(BATCH * G_KV * R_REP * (S_LEN / 64)), 256, 0, stream>>>(
        q_buf, k_buf, v_buf, mask_pm, a_out);

    gemm_o<<<dim3(2048 / 128, 2048 / 64), 256, 0, stream>>>(a_out, WoT, bo, x, out);
}

// Round 11
// 242.227 us; speedup vs baseline: 2.5508x; 1.0297x over previous
//
#include <hip/hip_runtime.h>

typedef unsigned short u16;
typedef unsigned int u32;
typedef __attribute__((ext_vector_type(8))) short bf16x8;
typedef __attribute__((ext_vector_type(4))) float f32x4;

#define HID 2048
#define S_LEN 1024
#define BATCH 2
#define G_KV 8
#define R_REP 4
#define HD 64
#define NQKV 3072  // 2048 q + 512 k + 512 v

__device__ __forceinline__ u16 f2bf(float f) {
    union { u32 u; float ff; } x; x.ff = f;
    u32 u = x.u;
    u += 0x7FFFu + ((u >> 16) & 1u);
    return (u16)(u >> 16);
}

__device__ __forceinline__ void gload_lds16(const void* g, void* l) {
    __builtin_amdgcn_global_load_lds((const __attribute__((address_space(1))) void*)g,
                                     (__attribute__((address_space(3))) void*)l,
                                     16, 0, 0);
}

// ------- fp32 -> bf16 bulk convert (x) -------
__global__ __launch_bounds__(256) void cvt_x(const float* __restrict__ in,
                                             u16* __restrict__ out) {
    int i = (blockIdx.x * 256 + threadIdx.x) * 8;
    float4 a = *(const float4*)(in + i);
    float4 b = *(const float4*)(in + i + 4);
    u16 t[8] = {f2bf(a.x), f2bf(a.y), f2bf(a.z), f2bf(a.w),
                f2bf(b.x), f2bf(b.y), f2bf(b.z), f2bf(b.w)};
    *(uint4*)(out + i) = *(const uint4*)t;
}

// ------- mask permute (S^T orientation): fp32 [B][S][S] -> fp32 fragment-order -------
// thread t=(w,quad,l16): q = w*16+l16, key(mt,reg) = mt*16+quad*4+reg
// out[((b*16+qblk)*16+kt)*4096 + t*16 + mt*4 + reg] = mask[b][qblk*64+q][kt*64+key]
__global__ __launch_bounds__(256) void mask_perm(const float* __restrict__ mask,
                                                 float* __restrict__ out) {
    __shared__ float tile[64 * 68];
    int bid = blockIdx.x;                 // 512 = B*16*16
    int kt = bid & 15, qblk = (bid >> 4) & 15, b = bid >> 8;
    int t = threadIdx.x;
    int row = t >> 2, c0 = (t & 3) * 16;
    const float* src = mask + ((size_t)b * S_LEN + qblk * 64 + row) * S_LEN + kt * 64 + c0;
#pragma unroll
    for (int i = 0; i < 4; ++i)
        *(float4*)&tile[row * 68 + c0 + i * 4] = *(const float4*)(src + i * 4);
    __syncthreads();
    int w = t >> 6, quad = (t >> 4) & 3, l16 = t & 15;
    int q = w * 16 + l16;
    float* dst = out + (size_t)bid * 4096 + t * 16;
#pragma unroll
    for (int mt = 0; mt < 4; ++mt) {
        float4 v = *(const float4*)&tile[q * 68 + mt * 16 + quad * 4];
        *(float4*)(dst + mt * 4) = v;
    }
}

// ------- Fused W transpose+convert: {Wq|Wk|Wv} fp32 [2048][*] -> WqkvT bf16 [3072][2048] -------
__global__ __launch_bounds__(256) void transpose_qkv(const float* __restrict__ Wq,
                                                     const float* __restrict__ Wk,
                                                     const float* __restrict__ Wv,
                                                     u16* __restrict__ out) {
    __shared__ float tile[32][33];
    int n0 = blockIdx.x * 32, k0 = blockIdx.y * 32;
    const float* in; int N, nc0;
    if (n0 < 2048)      { in = Wq; N = 2048; nc0 = n0; }
    else if (n0 < 2560) { in = Wk; N = 512;  nc0 = n0 - 2048; }
    else                { in = Wv; N = 512;  nc0 = n0 - 2560; }
    int tx = threadIdx.x, ty = threadIdx.y;
#pragma unroll
    for (int j = 0; j < 4; ++j)
        tile[ty + j * 8][tx] = in[(size_t)(k0 + ty + j * 8) * N + nc0 + tx];
    __syncthreads();
#pragma unroll
    for (int j = 0; j < 4; ++j)
        out[(size_t)(n0 + ty + j * 8) * 2048 + k0 + tx] = f2bf(tile[tx][ty + j * 8]);
}

// ------- Transpose+convert: in fp32 [K][N] -> out bf16 [N][K] -------
__global__ __launch_bounds__(256) void transpose_cvt(const float* __restrict__ in,
                                                     u16* __restrict__ out,
                                                     int K, int N) {
    __shared__ float tile[32][33];
    int n0 = blockIdx.x * 32, k0 = blockIdx.y * 32;
    int tx = threadIdx.x, ty = threadIdx.y;
#pragma unroll
    for (int j = 0; j < 4; ++j)
        tile[ty + j * 8][tx] = in[(size_t)(k0 + ty + j * 8) * N + n0 + tx];
    __syncthreads();
#pragma unroll
    for (int j = 0; j < 4; ++j)
        out[(size_t)(n0 + ty + j * 8) * K + k0 + tx] = f2bf(tile[tx][ty + j * 8]);
}

// ------- QKV GEMM: BM=64 BN=128 BK=32, 768 blocks (3/CU); q pre-scaled; V^T -------
__global__ __launch_bounds__(256) void gemm_qkv(const u16* __restrict__ Xb,
                                                const u16* __restrict__ WT,
                                                const float* __restrict__ bq,
                                                const float* __restrict__ bk,
                                                const float* __restrict__ bv,
                                                u16* __restrict__ qb,
                                                u16* __restrict__ kb,
                                                u16* __restrict__ vb) {
    __shared__ __align__(16) u16 As[64 * 32];
    __shared__ __align__(16) u16 Bs[128 * 32];
    int tid = threadIdx.x;
    int w = tid >> 6, lane = tid & 63, quad = lane >> 4, l16 = lane & 15;
    int m0 = blockIdx.y * 64, n0 = blockIdx.x * 128;
    int wr = (w >> 1) * 32, wc = (w & 1) * 64;   // wave tile 32x64
    int srow = lane >> 2, scol = (lane & 3) * 8;

    f32x4 acc[2][4];
#pragma unroll
    for (int i = 0; i < 2; ++i)
#pragma unroll
        for (int j = 0; j < 4; ++j) acc[i][j] = (f32x4){0.f, 0.f, 0.f, 0.f};

    for (int k0 = 0; k0 < 2048; k0 += 32) {
        gload_lds16(&Xb[(size_t)(m0 + w * 16 + srow) * 2048 + k0 + scol], &As[(w * 16) * 32]);
#pragma unroll
        for (int c = 0; c < 2; ++c) {
            int row = w * 32 + c * 16;
            gload_lds16(&WT[(size_t)(n0 + row + srow) * 2048 + k0 + scol], &Bs[row * 32]);
        }
        __syncthreads();
        bf16x8 af[2], bfr[4];
#pragma unroll
        for (int mt = 0; mt < 2; ++mt)
            af[mt] = *(const bf16x8*)&As[(wr + mt * 16 + l16) * 32 + quad * 8];
#pragma unroll
        for (int nt = 0; nt < 4; ++nt)
            bfr[nt] = *(const bf16x8*)&Bs[(wc + nt * 16 + l16) * 32 + quad * 8];
#pragma unroll
        for (int mt = 0; mt < 2; ++mt)
#pragma unroll
            for (int nt = 0; nt < 4; ++nt)
                acc[mt][nt] = __builtin_amdgcn_mfma_f32_16x16x32_bf16(af[mt], bfr[nt], acc[mt][nt], 0, 0, 0);
        __syncthreads();
    }

#pragma unroll
    for (int nt = 0; nt < 4; ++nt) {
        int n = n0 + wc + nt * 16 + l16;
        float bias;
        if (n < 2048) bias = bq[n];
        else if (n < 2560) bias = bk[n - 2048];
        else bias = bv[n - 2560];
#pragma unroll
        for (int mt = 0; mt < 2; ++mt) {
#pragma unroll
            for (int reg = 0; reg < 4; ++reg) {
                int m = m0 + wr + mt * 16 + quad * 4 + reg;
                float val = acc[mt][nt][reg] + bias;
                int b = m >> 10, s = m & 1023;
                if (n < 2048) {
                    int g = n >> 8, r = (n >> 6) & 3, d = n & 63;
                    qb[((((size_t)(b * G_KV + g) * R_REP + r) * S_LEN) + s) * HD + d] = f2bf(val * 0.125f);
                } else if (n < 2560) {
                    int n2 = n - 2048, g = n2 >> 6, d = n2 & 63;
                    kb[(((size_t)(b * G_KV + g) * S_LEN) + s) * HD + d] = f2bf(val);
                } else {
                    int n2 = n - 2560, g = n2 >> 6, d = n2 & 63;
                    vb[(((size_t)(b * G_KV + g) * HD + d) * S_LEN) + s] = f2bf(val);  // V^T
                }
            }
        }
    }
}

// ------- Attention: MFMA flash, S^T orientation (S^T = K·Q^T) -------
// Lane (w,quad,l16): softmax owns q=w*16+l16, keys mt*16+quad*4+reg (consecutive!).
// P writes: 4 x ds_write_b64 (packed bf16). PV reads unchanged. l reduced once at end.
__global__ __launch_bounds__(256) void attn_mfma(const u16* __restrict__ qbuf,
                                                 const u16* __restrict__ kbuf,
                                                 const u16* __restrict__ vtbuf,
                                                 const float* __restrict__ mask_pm,
                                                 u16* __restrict__ aout) {
    __shared__ __align__(16) u16 Ks[64 * 72];   // [key][dim]
    __shared__ __align__(16) u16 Vs[64 * 72];   // [dim][key]
    __shared__ __align__(16) u16 Ps[64 * 72];   // [q][key] bf16 (wave-private strips)
    __shared__ float l_lds[64];

    int d = blockIdx.x;
    int xcd = d & 7, j = d >> 3;
    int pr = xcd * 2 + (j >> 6);          // (b,g) pair 0..15
    int r = (j >> 4) & 3, qblk = j & 15;
    int b = pr >> 3, g = pr & 7;

    int tid = threadIdx.x;
    int w = tid >> 6, lane = tid & 63, quad = lane >> 4, l16 = lane & 15;
    int s0 = qblk * 64;
    int q = w * 16 + l16;                 // this lane's softmax q-row

    const u16* qrow = qbuf +
        ((((size_t)(b * G_KV + g) * R_REP + r) * S_LEN) + s0 + q) * HD;
    bf16x8 qf0 = *(const bf16x8*)(qrow + quad * 8);
    bf16x8 qf1 = *(const bf16x8*)(qrow + 32 + quad * 8);

    f32x4 o_acc[4];
#pragma unroll
    for (int i = 0; i < 4; ++i) o_acc[i] = (f32x4){0.f, 0.f, 0.f, 0.f};
    float l_part = 0.f;

    const u16* kbase  = kbuf  + (size_t)(b * G_KV + g) * S_LEN * HD;
    const u16* vtbase = vtbuf + (size_t)(b * G_KV + g) * HD * S_LEN;
    const float* mbase = mask_pm + ((size_t)(b * 16 + qblk) * 16) * 4096 + tid * 16;

    int srow = tid >> 2, sc = (tid & 3) * 16;

    // prologue: prefetch tile 0
    uint4 kp0, kp1, vp0, vp1;
    f32x4 mc[4], mn[4];
    {
        const u16* kr = kbase + (size_t)srow * HD + sc;
        kp0 = *(const uint4*)kr; kp1 = *(const uint4*)(kr + 8);
        const u16* vr = vtbase + (size_t)srow * S_LEN + sc;
        vp0 = *(const uint4*)vr; vp1 = *(const uint4*)(vr + 8);
#pragma unroll
        for (int i = 0; i < 4; ++i) mc[i] = *(const f32x4*)(mbase + i * 4);
    }

    for (int kt = 0; kt < 16; ++kt) {
        __syncthreads();    // prior iteration's LDS reads complete
        *(uint4*)&Ks[srow * 72 + sc]     = kp0;
        *(uint4*)&Ks[srow * 72 + sc + 8] = kp1;
        *(uint4*)&Vs[srow * 72 + sc]     = vp0;
        *(uint4*)&Vs[srow * 72 + sc + 8] = vp1;
        __syncthreads();    // staging visible

        // prefetch kt+1 (overlaps compute)
        if (kt < 15) {
            int nk = (kt + 1) * 64;
            const u16* kr = kbase + (size_t)(nk + srow) * HD + sc;
            kp0 = *(const uint4*)kr; kp1 = *(const uint4*)(kr + 8);
            const u16* vr = vtbase + (size_t)srow * S_LEN + nk + sc;
            vp0 = *(const uint4*)vr; vp1 = *(const uint4*)(vr + 8);
            const float* mr = mbase + (size_t)(kt + 1) * 4096;
#pragma unroll
            for (int i = 0; i < 4; ++i) mn[i] = *(const f32x4*)(mr + i * 4);
        }

        // S^T = K * Q^T : A = K tile rows (keys), B = Q regs
#pragma unroll
        for (int mt = 0; mt < 4; ++mt) {
            bf16x8 af0 = *(const bf16x8*)&Ks[(mt * 16 + l16) * 72 + quad * 8];
            bf16x8 af1 = *(const bf16x8*)&Ks[(mt * 16 + l16) * 72 + 32 + quad * 8];
            f32x4 z = (f32x4){0.f, 0.f, 0.f, 0.f};
            z = __builtin_amdgcn_mfma_f32_16x16x32_bf16(af0, qf0, z, 0, 0, 0);
            f32x4 s = __builtin_amdgcn_mfma_f32_16x16x32_bf16(af1, qf1, s = z, 0, 0, 0);

            // softmax: 4 consecutive keys for this lane's q; round-half-up pack
            u32 er[4];
#pragma unroll
            for (int rg = 0; rg < 4; ++rg) {
                float e = __expf(s[rg] * mc[mt][rg]);
                u32 u = __float_as_uint(e) + 0x8000u;
                er[rg] = u;
                l_part += __uint_as_float(u & 0xFFFF0000u);  // consistent with stored P
            }
            uint2 pk;
            pk.x = __builtin_amdgcn_perm(er[1], er[0], 0x07060302u);
            pk.y = __builtin_amdgcn_perm(er[3], er[2], 0x07060302u);
            *(uint2*)&Ps[q * 72 + mt * 16 + quad * 4] = pk;   // wave-private strip
        }
        // no barrier: P strips are wave-private; in-wave DS ordering + lgkmcnt suffice

        // PV: O = P * V  (A = P fragments, B = V^T tiles)
        bf16x8 pf0 = *(const bf16x8*)&Ps[q * 72 + quad * 8];
        bf16x8 pf1 = *(const bf16x8*)&Ps[q * 72 + 32 + quad * 8];
#pragma unroll
        for (int nt = 0; nt < 4; ++nt) {
            bf16x8 vf0 = *(const bf16x8*)&Vs[(nt * 16 + l16) * 72 + quad * 8];
            bf16x8 vf1 = *(const bf16x8*)&Vs[(nt * 16 + l16) * 72 + 32 + quad * 8];
            o_acc[nt] = __builtin_amdgcn_mfma_f32_16x16x32_bf16(pf0, vf0, o_acc[nt], 0, 0, 0);
            o_acc[nt] = __builtin_amdgcn_mfma_f32_16x16x32_bf16(pf1, vf1, o_acc[nt], 0, 0, 0);
        }
        // rotate mask prefetch
#pragma unroll
        for (int i = 0; i < 4; ++i) mc[i] = mn[i];
    }

    // final l reduction: sum across quads (lanes with same l16), then in-wave transpose
    l_part += __shfl_xor(l_part, 16);
    l_part += __shfl_xor(l_part, 32);
    l_lds[w * 16 + l16] = l_part;        // wave-private strip write
    // read pattern below is same-wave; compiler orders DS ops

#pragma unroll
    for (int reg = 0; reg < 4; ++reg) {
        int row = w * 16 + quad * 4 + reg;
        float inv = 1.0f / l_lds[row];
        int sidx = s0 + row;
        u16* dst = aout + ((size_t)(b * S_LEN + sidx)) * HID + (g * R_REP + r) * HD;
#pragma unroll
        for (int nt = 0; nt < 4; ++nt)
            dst[nt * 16 + l16] = f2bf(o_acc[nt][reg] * inv);
    }
}

// ------- Output GEMM: BM=64 BN=128, 512 blocks (2/CU); fp32 out + bias + residual -------
__global__ __launch_bounds__(256) void gemm_o(const u16* __restrict__ A,
                                              const u16* __restrict__ WT,
                                              const float* __restrict__ bo,
                                              const float* __restrict__ Xres,
                                              float* __restrict__ out) {
    __shared__ __align__(16) u16 As[64 * 32];
    __shared__ __align__(16) u16 Bs[128 * 32];
    int tid = threadIdx.x;
    int w = tid >> 6, lane = tid & 63, quad = lane >> 4, l16 = lane & 15;
    int m0 = blockIdx.y * 64, n0 = blockIdx.x * 128;
    int wr = (w >> 1) * 32, wc = (w & 1) * 64;
    int srow = lane >> 2, scol = (lane & 3) * 8;

    f32x4 acc[2][4];
#pragma unroll
    for (int i = 0; i < 2; ++i)
#pragma unroll
        for (int j = 0; j < 4; ++j) acc[i][j] = (f32x4){0.f, 0.f, 0.f, 0.f};

    for (int k0 = 0; k0 < 2048; k0 += 32) {
        gload_lds16(&A[(size_t)(m0 + w * 16 + srow) * 2048 + k0 + scol], &As[(w * 16) * 32]);
#pragma unroll
        for (int c = 0; c < 2; ++c) {
            int row = w * 32 + c * 16;
            gload_lds16(&WT[(size_t)(n0 + row + srow) * 2048 + k0 + scol], &Bs[row * 32]);
        }
        __syncthreads();
        bf16x8 af[2], bfr[4];
#pragma unroll
        for (int mt = 0; mt < 2; ++mt)
            af[mt] = *(const bf16x8*)&As[(wr + mt * 16 + l16) * 32 + quad * 8];
#pragma unroll
        for (int nt = 0; nt < 4; ++nt)
            bfr[nt] = *(const bf16x8*)&Bs[(wc + nt * 16 + l16) * 32 + quad * 8];
#pragma unroll
        for (int mt = 0; mt < 2; ++mt)
#pragma unroll
            for (int nt = 0; nt < 4; ++nt)
                acc[mt][nt] = __builtin_amdgcn_mfma_f32_16x16x32_bf16(af[mt], bfr[nt], acc[mt][nt], 0, 0, 0);
        __syncthreads();
    }

#pragma unroll
    for (int nt = 0; nt < 4; ++nt) {
        int n = n0 + wc + nt * 16 + l16;
        float bias = bo[n];
#pragma unroll
        for (int mt = 0; mt < 2; ++mt) {
#pragma unroll
            for (int reg = 0; reg < 4; ++reg) {
                int m = m0 + wr + mt * 16 + quad * 4 + reg;
                out[(size_t)m * 2048 + n] = acc[mt][nt][reg] + bias + Xres[(size_t)m * 2048 + n];
            }
        }
    }
}

extern "C" void kernel_launch(void* const* d_in, const int* in_sizes, int n_in,
                              void* d_out, int out_size, void* d_ws, size_t ws_size,
                              hipStream_t stream) {
    const float* x    = (const float*)d_in[0];
    const float* mask = (const float*)d_in[1];
    const float* Wq   = (const float*)d_in[2];
    const float* bq   = (const float*)d_in[3];
    const float* Wk   = (const float*)d_in[4];
    const float* bk   = (const float*)d_in[5];
    const float* Wv   = (const float*)d_in[6];
    const float* bv   = (const float*)d_in[7];
    const float* Wo   = (const float*)d_in[8];
    const float* bo   = (const float*)d_in[9];
    float* out = (float*)d_out;

    u16* ws = (u16*)d_ws;
    size_t off = 0;
    u16* WqkvT = ws + off; off += (size_t)NQKV * 2048;
    u16* WoT   = ws + off; off += (size_t)2048 * 2048;
    u16* q_buf = ws + off; off += (size_t)BATCH * G_KV * R_REP * S_LEN * HD;
    u16* k_buf = ws + off; off += (size_t)BATCH * G_KV * S_LEN * HD;
    u16* v_buf = ws + off; off += (size_t)BATCH * G_KV * S_LEN * HD;  // transposed [b][g][d][s]
    u16* a_out = ws + off; off += (size_t)2048 * 2048;
    u16* Xb       = a_out;            // alias: consumed by gemm_qkv before attn writes a_out
    float* mask_pm = (float*)WqkvT;   // alias: WqkvT (12.6 MB) dead after gemm_qkv; need 8 MB

    cvt_x<<<dim3(2048 * 2048 / (256 * 8)), 256, 0, stream>>>(x, Xb);

    dim3 tb(32, 8);
    transpose_qkv<<<dim3(96, 64), tb, 0, stream>>>(Wq, Wk, Wv, WqkvT);
    transpose_cvt<<<dim3(64, 64), tb, 0, stream>>>(Wo, WoT, 2048, 2048);

    gemm_qkv<<<dim3(NQKV / 128, 2048 / 64), 256, 0, stream>>>(Xb, WqkvT, bq, bk, bv,
                                                              q_buf, k_buf, v_buf);

    mask_perm<<<dim3(BATCH * 16 * 16), 256, 0, stream>>>(mask, mask_pm);

    attn_mfma<<<dim3(BATCH * G_KV * R_REP * (S_LEN / 64)), 256, 0, stream>>>(
        q_buf, k_buf, v_buf, mask_pm, a_out);

    gemm_o<<<dim3(2048 / 128, 2048 / 64), 256, 0, stream>>>(a_out, WoT, bo, x, out);
}